// Round 1
// baseline (2751.926 us; speedup 1.0000x reference)
//
#include <hip/hip_runtime.h>
#include <hip/hip_bf16.h>
#include <hip/hip_runtime_api.h>

#define BT 16
#define CCH 64
#define MIDC 32
#define H 128
#define W 128
#define KS 16
#define STR 8
#define NH 15
#define NW 15
#define L 225
#define HW (H * W)

__device__ __forceinline__ float lrelu(float v) { return v > 0.f ? v : 0.2f * v; }

// ---------------------------------------------------------------------------
// Kernel A: BasicBlock: reflect-pad conv3x3 (64->32) + lrelu + conv1x1 (32->64)
// + lrelu  ->  f  (in workspace)
// Weights are read with wave-uniform indices -> compiler scalarizes (s_load).
// ---------------------------------------------------------------------------
__global__ __launch_bounds__(256) void basic_block_k(
    const float* __restrict__ fea, const float* __restrict__ W1,
    const float* __restrict__ W2, float* __restrict__ f) {
  __shared__ float s_in[16][18][18];  // 16 input channels, 18x18 (tile+halo)
  const int b = blockIdx.z;
  const int ty0 = blockIdx.y * 16, tx0 = blockIdx.x * 16;
  const int tid = threadIdx.x;
  const int py = tid >> 4, px = tid & 15;

  float acc[MIDC];
#pragma unroll
  for (int mc = 0; mc < MIDC; ++mc) acc[mc] = 0.f;

  for (int cc = 0; cc < 4; ++cc) {  // 4 chunks of 16 input channels
    __syncthreads();
    for (int i = tid; i < 16 * 18 * 18; i += 256) {
      int ic = i / 324, r = i - ic * 324;
      int iy = r / 18, ix = r - iy * 18;
      int gy = ty0 + iy - 1, gx = tx0 + ix - 1;
      gy = gy < 0 ? -gy : (gy > 127 ? 254 - gy : gy);
      gx = gx < 0 ? -gx : (gx > 127 ? 254 - gx : gx);
      s_in[ic][iy][ix] = fea[((b * CCH + cc * 16 + ic) * H + gy) * W + gx];
    }
    __syncthreads();
#pragma unroll 4
    for (int icl = 0; icl < 16; ++icl) {
      float v[9];
#pragma unroll
      for (int dy = 0; dy < 3; ++dy)
#pragma unroll
        for (int dx = 0; dx < 3; ++dx)
          v[dy * 3 + dx] = s_in[icl][py + dy][px + dx];
      const float* w1p = W1 + (cc * 16 + icl) * 9;  // + mc*64*9
#pragma unroll
      for (int mc = 0; mc < MIDC; ++mc) {
        float a = acc[mc];
#pragma unroll
        for (int k = 0; k < 9; ++k) a += v[k] * w1p[mc * CCH * 9 + k];
        acc[mc] = a;
      }
    }
  }
#pragma unroll
  for (int mc = 0; mc < MIDC; ++mc) acc[mc] = lrelu(acc[mc]);

  const int y = ty0 + py, x = tx0 + px;
  const int base = b * CCH * HW + y * W + x;
#pragma unroll 4
  for (int oc = 0; oc < CCH; ++oc) {
    float s = 0.f;
#pragma unroll
    for (int mc = 0; mc < MIDC; ++mc) s += W2[oc * MIDC + mc] * acc[mc];
    f[base + oc * HW] = lrelu(s);
  }
}

// ---------------------------------------------------------------------------
// Kernel B: spatial-graph matmul + fold.
// One block per (b, ky, kx). fs[c][q] = f[b,c, 8*qy+ky, 8*qx+kx] staged in LDS.
// G[c,p] = sum_q fs[c][q] * spa[b][p][q];  atomicAdd into x at (8*py+ky, 8*px+kx).
// Thread layout: tp = tid>>2 (patch base), tc = tid&3 (16-channel group);
// each thread: acc[16 ch][4 patches] register block (~1.3 instr/FMA).
// ---------------------------------------------------------------------------
__global__ __launch_bounds__(256) void spa_fold_k(
    const float* __restrict__ f, const float* __restrict__ spa,
    float* __restrict__ x) {
  __shared__ float fs[CCH][L];  // 57.6 KB
  const int kx = blockIdx.x, ky = blockIdx.y, b = blockIdx.z;
  const int tid = threadIdx.x;

  for (int i = tid; i < CCH * L; i += 256) {
    int c = i / L, q = i - c * L;
    int qy = q / NW, qx = q - qy * NW;
    fs[c][q] = f[((b * CCH + c) * H + qy * STR + ky) * W + qx * STR + kx];
  }
  __syncthreads();

  const int tp = tid >> 2, tc = tid & 3;
  float acc[16][4];
#pragma unroll
  for (int ci = 0; ci < 16; ++ci)
#pragma unroll
    for (int j = 0; j < 4; ++j) acc[ci][j] = 0.f;

  const float* sb = spa + b * L * L;
  const float* r0 = sb + tp * L;
  const float* r1 = sb + (tp + 64) * L;
  const float* r2 = sb + (tp + 128) * L;
  const float* r3 = sb + (tp + 192) * L;
  const bool ok3 = (tp + 192) < L;

  for (int q = 0; q < L; ++q) {
    float sp0 = r0[q];
    float sp1 = r1[q];
    float sp2 = r2[q];
    float sp3 = ok3 ? r3[q] : 0.f;
#pragma unroll
    for (int ci = 0; ci < 16; ++ci) {
      float v = fs[tc * 16 + ci][q];
      acc[ci][0] += v * sp0;
      acc[ci][1] += v * sp1;
      acc[ci][2] += v * sp2;
      acc[ci][3] += v * sp3;
    }
  }

#pragma unroll
  for (int j = 0; j < 4; ++j) {
    const int p = tp + 64 * j;
    if (p < L) {
      const int pyy = p / NW, pxx = p - pyy * NW;
      const int base =
          (b * CCH + tc * 16) * HW + (pyy * STR + ky) * W + pxx * STR + kx;
#pragma unroll
      for (int ci = 0; ci < 16; ++ci)
        atomicAdd(&x[base + ci * HW], acc[ci][j]);
    }
  }
}

// ---------------------------------------------------------------------------
// Kernel C: spectral residual + gated fusion.
// One thread per pixel column: res = spe[b] @ f_col; xa = 0.5*(x+res);
// xl = lrelu(Wl @ xa + bl); wei = sigmoid(xl); out = x*wei + res*(1-wei) + f.
// spe/Wl/bl accessed with wave-uniform indices -> scalar loads.
// x lives in d_out (accumulated by kernel B); overwritten with final output.
// ---------------------------------------------------------------------------
__global__ __launch_bounds__(256) void final_k(
    const float* __restrict__ f, const float* __restrict__ spe,
    const float* __restrict__ Wl, const float* __restrict__ bl,
    float* __restrict__ xo) {
  const int b = blockIdx.y;
  const int n = blockIdx.x * 256 + threadIdx.x;
  const int pb = b * CCH * HW + n;
  const float* sp = spe + b * CCH * CCH;

  float res[CCH];
#pragma unroll
  for (int c = 0; c < CCH; ++c) res[c] = 0.f;

  for (int dc = 0; dc < 4; ++dc) {  // chunks of 16 f-channels
    float vf[16];
#pragma unroll
    for (int dd = 0; dd < 16; ++dd) vf[dd] = f[pb + (dc * 16 + dd) * HW];
#pragma unroll
    for (int c = 0; c < CCH; ++c) {
      float a = res[c];
      const float* sr = sp + c * CCH + dc * 16;
#pragma unroll
      for (int dd = 0; dd < 16; ++dd) a += sr[dd] * vf[dd];
      res[c] = a;
    }
  }

  float xa[CCH];
#pragma unroll
  for (int c = 0; c < CCH; ++c) xa[c] = 0.5f * (xo[pb + c * HW] + res[c]);

#pragma unroll 4
  for (int c = 0; c < CCH; ++c) {
    float t = bl[c];
    const float* wr = Wl + c * CCH;
#pragma unroll
    for (int j = 0; j < CCH; ++j) t += wr[j] * xa[j];
    t = lrelu(t);
    const float wei = 1.f / (1.f + __expf(-t));
    const float xv = 2.f * xa[c] - res[c];  // recover x without re-read
    xo[pb + c * HW] = xv * wei + res[c] * (1.f - wei) + f[pb + c * HW];
  }
}

// ---------------------------------------------------------------------------
extern "C" void kernel_launch(void* const* d_in, const int* in_sizes, int n_in,
                              void* d_out, int out_size, void* d_ws,
                              size_t ws_size, hipStream_t stream) {
  const float* fea = (const float*)d_in[0];
  const float* spa = (const float*)d_in[1];
  const float* spe = (const float*)d_in[2];
  const float* W1  = (const float*)d_in[3];
  const float* W2  = (const float*)d_in[4];
  const float* Wl  = (const float*)d_in[5];
  const float* bl  = (const float*)d_in[6];
  float* out = (float*)d_out;
  float* f   = (float*)d_ws;  // 64 MB: BasicBlock output

  hipMemsetAsync(d_out, 0, (size_t)out_size * sizeof(float), stream);
  basic_block_k<<<dim3(8, 8, BT), 256, 0, stream>>>(fea, W1, W2, f);
  spa_fold_k<<<dim3(KS, KS, BT), 256, 0, stream>>>(f, spa, out);
  final_k<<<dim3(HW / 256, BT), 256, 0, stream>>>(f, spe, Wl, bl, out);
}

// Round 3
// 860.065 us; speedup vs baseline: 3.1997x; 3.1997x over previous
//
#include <hip/hip_runtime.h>
#include <hip/hip_bf16.h>
#include <hip/hip_runtime_api.h>

#define BT 16
#define CCH 64
#define MIDC 32
#define H 128
#define W 128
#define KS 16
#define STR 8
#define NH 15
#define NW 15
#define L 225
#define HW (H * W)

// padded spa_bf geometry
#define PN 240   // p padded to 240 (15 ntiles of 16)
#define PK 256   // q padded to 256 (8 k-steps of 32)
// LDS A-tile pitch (bf16 elems per row): >=256, 16B-multiple, avoids pow2 banks
#define APITCH 264
// LDS output accumulator pitch per channel (floats)
#define GPITCH 260

typedef __attribute__((ext_vector_type(8))) short short8;
typedef __attribute__((ext_vector_type(4))) float f32x4;

__device__ __forceinline__ float lrelu(float v) { return v > 0.f ? v : 0.2f * v; }

// ---------------------------------------------------------------------------
// Kernel A: BasicBlock: reflect-pad conv3x3 (64->32) + lrelu + conv1x1 (32->64)
// + lrelu -> f (fp32, ws) + bf16 copy fbf for the MFMA path.
// ---------------------------------------------------------------------------
__global__ __launch_bounds__(256) void basic_block_k(
    const float* __restrict__ fea, const float* __restrict__ W1,
    const float* __restrict__ W2, float* __restrict__ f,
    __hip_bfloat16* __restrict__ fbf) {
  __shared__ float s_in[16][18][18];
  const int b = blockIdx.z;
  const int ty0 = blockIdx.y * 16, tx0 = blockIdx.x * 16;
  const int tid = threadIdx.x;
  const int py = tid >> 4, px = tid & 15;

  float acc[MIDC];
#pragma unroll
  for (int mc = 0; mc < MIDC; ++mc) acc[mc] = 0.f;

  for (int cc = 0; cc < 4; ++cc) {
    __syncthreads();
    for (int i = tid; i < 16 * 18 * 18; i += 256) {
      int ic = i / 324, r = i - ic * 324;
      int iy = r / 18, ix = r - iy * 18;
      int gy = ty0 + iy - 1, gx = tx0 + ix - 1;
      gy = gy < 0 ? -gy : (gy > 127 ? 254 - gy : gy);
      gx = gx < 0 ? -gx : (gx > 127 ? 254 - gx : gx);
      s_in[ic][iy][ix] = fea[((b * CCH + cc * 16 + ic) * H + gy) * W + gx];
    }
    __syncthreads();
#pragma unroll 4
    for (int icl = 0; icl < 16; ++icl) {
      float v[9];
#pragma unroll
      for (int dy = 0; dy < 3; ++dy)
#pragma unroll
        for (int dx = 0; dx < 3; ++dx)
          v[dy * 3 + dx] = s_in[icl][py + dy][px + dx];
      const float* w1p = W1 + (cc * 16 + icl) * 9;
#pragma unroll
      for (int mc = 0; mc < MIDC; ++mc) {
        float a = acc[mc];
#pragma unroll
        for (int k = 0; k < 9; ++k) a += v[k] * w1p[mc * CCH * 9 + k];
        acc[mc] = a;
      }
    }
  }
#pragma unroll
  for (int mc = 0; mc < MIDC; ++mc) acc[mc] = lrelu(acc[mc]);

  const int y = ty0 + py, x = tx0 + px;
  const int base = b * CCH * HW + y * W + x;
#pragma unroll 4
  for (int oc = 0; oc < CCH; ++oc) {
    float s = 0.f;
#pragma unroll
    for (int mc = 0; mc < MIDC; ++mc) s += W2[oc * MIDC + mc] * acc[mc];
    s = lrelu(s);
    f[base + oc * HW] = s;
    if (fbf) fbf[base + oc * HW] = __float2bfloat16(s);
  }
}

// ---------------------------------------------------------------------------
// Prep: spa (fp32 [b][225][225]) -> spa_bf (bf16 [b][240][256], zero-padded)
// ---------------------------------------------------------------------------
__global__ __launch_bounds__(256) void spa_prep_k(
    const float* __restrict__ spa, __hip_bfloat16* __restrict__ spa_bf) {
  const int idx = blockIdx.x * 256 + threadIdx.x;  // b*PN*PK total
  const int b = idx / (PN * PK);
  const int r = idx - b * (PN * PK);
  const int p = r >> 8, q = r & 255;
  float v = (p < L && q < L) ? spa[(b * L + p) * L + q] : 0.f;
  spa_bf[idx] = __float2bfloat16(v);
}

// ---------------------------------------------------------------------------
// Kernel B (MFMA): spatial-graph matmul + fused overlap-add fold, no atomics.
// Block = (b, ky0, kx0), ky0,kx0 in [0,8). Owns output pixels
// {y = 8*yi + ky0, x = 8*xi + kx0 : yi,xi in [0,16)}; computes the 4 (ky,kx)
// variants {ky0,ky0+8} x {kx0,kx0+8} that fold onto exactly those pixels.
// Per variant: G = fs(64x225) @ spa^T via 16x16x32 bf16 MFMA, merged into LDS
// gout[c][yi][xi] with PLAIN adds: within a variant every (c,yi,xi) target is
// written by exactly one lane (channels partition by wave/mi/reg; p->(yi,xi)
// injective), and variants are barrier-separated by the staging syncs.
// 512 threads = 8 waves: wave w -> mtiles {(w>>2)*2,+1}, ntiles (w&3)*4..+3.
// ---------------------------------------------------------------------------
__global__ __launch_bounds__(512) void spa_mfma_k(
    const __hip_bfloat16* __restrict__ fbf,
    const __hip_bfloat16* __restrict__ spa_bf, float* __restrict__ x) {
  __shared__ __align__(16) short fs[CCH * APITCH];      // bf16 A tile, 33.8 KB
  __shared__ __align__(16) float gout[CCH * GPITCH];    // fp32 out acc, 66.6 KB

  // XCD-affine remap (bijective: 1024 = 8*128): one XCD gets 128 consecutive
  // lb values = 2 full batches -> fbf/spa_bf slices stay in that XCD's L2.
  const int lb = ((int)blockIdx.x % 8) * 128 + (int)blockIdx.x / 8;
  const int b = lb >> 6, ky0 = (lb >> 3) & 7, kx0 = lb & 7;
  const int tid = threadIdx.x;

  for (int i = tid; i < CCH * GPITCH; i += 512) gout[i] = 0.f;

  const int w = tid >> 6, lane = tid & 63;
  const int lm = lane & 15, lk = lane >> 4;
  const int mt0 = (w >> 2) * 2;       // 0 or 2
  const int nt0 = (w & 3) * 4;        // 0,4,8,12
  const int nnt = ((w & 3) == 3) ? 3 : 4;

  const unsigned short* fb = (const unsigned short*)fbf + (size_t)b * CCH * HW;
  const short* sb = (const short*)spa_bf + (size_t)b * PN * PK;

#pragma unroll 1
  for (int v = 0; v < 4; ++v) {
    const int vy = v >> 1, vx = v & 1;
    const int ky = ky0 + 8 * vy, kx = kx0 + 8 * vx;

    __syncthreads();  // prior variant's MFMA reads + gout merges done
    for (int i = tid; i < CCH * 256; i += 512) {
      const int c = i >> 8, q = i & 255;
      short val = 0;
      if (q < L) {
        const int qy = q / NW, qx = q - qy * NW;
        val = (short)fb[(c * H + qy * STR + ky) * W + qx * STR + kx];
      }
      fs[c * APITCH + q] = val;
    }
    __syncthreads();

    f32x4 acc[2][4];
#pragma unroll
    for (int mi = 0; mi < 2; ++mi)
#pragma unroll
      for (int n = 0; n < 4; ++n) acc[mi][n] = (f32x4){0.f, 0.f, 0.f, 0.f};

#pragma unroll 1
    for (int K0 = 0; K0 < PK; K0 += 32) {
      const int ko = K0 + 8 * lk;
      short8 a0 = *(const short8*)&fs[(mt0 * 16 + lm) * APITCH + ko];
      short8 a1 = *(const short8*)&fs[((mt0 + 1) * 16 + lm) * APITCH + ko];
#pragma unroll
      for (int n = 0; n < 4; ++n) {
        if (n < nnt) {
          short8 bb = *(const short8*)&sb[((nt0 + n) * 16 + lm) * PK + ko];
          acc[0][n] = __builtin_amdgcn_mfma_f32_16x16x32_bf16(a0, bb, acc[0][n], 0, 0, 0);
          acc[1][n] = __builtin_amdgcn_mfma_f32_16x16x32_bf16(a1, bb, acc[1][n], 0, 0, 0);
        }
      }
    }

    // Merge D into gout at the fold-shifted position. c = (mt0+mi)*16+lk*4+r,
    // p = (nt0+n)*16+lm  ->  (yi,xi) = (qy+vy, qx+vx). Plain adds (see above).
#pragma unroll
    for (int mi = 0; mi < 2; ++mi) {
#pragma unroll
      for (int n = 0; n < 4; ++n) {
        if (n >= nnt) continue;
        const int p = (nt0 + n) * 16 + lm;
        if (p >= L) continue;
        const int qy = p / NW, qx = p - qy * NW;
        const int yi = qy + vy, xi = qx + vx;
        float* g = &gout[((mt0 + mi) * 16 + lk * 4) * GPITCH + yi * 16 + xi];
#pragma unroll
        for (int r = 0; r < 4; ++r) g[r * GPITCH] += acc[mi][n][r];
      }
    }
  }

  __syncthreads();
  float* xb = x + (size_t)b * CCH * HW;
  for (int i = tid; i < CCH * 256; i += 512) {
    const int c = i >> 8, yi = (i >> 4) & 15, xi = i & 15;
    xb[(c * H + yi * STR + ky0) * W + xi * STR + kx0] =
        gout[c * GPITCH + yi * 16 + xi];
  }
}

// ---------------------------------------------------------------------------
// Fallback kernel (fp32 + atomics) when ws is too small for the MFMA path.
// ---------------------------------------------------------------------------
__global__ __launch_bounds__(256) void spa_fold_k(
    const float* __restrict__ f, const float* __restrict__ spa,
    float* __restrict__ x) {
  __shared__ float fsh[CCH][L];
  const int kx = blockIdx.x, ky = blockIdx.y, b = blockIdx.z;
  const int tid = threadIdx.x;

  for (int i = tid; i < CCH * L; i += 256) {
    int c = i / L, q = i - c * L;
    int qy = q / NW, qx = q - qy * NW;
    fsh[c][q] = f[((b * CCH + c) * H + qy * STR + ky) * W + qx * STR + kx];
  }
  __syncthreads();

  const int tp = tid >> 2, tc = tid & 3;
  float acc[16][4];
#pragma unroll
  for (int ci = 0; ci < 16; ++ci)
#pragma unroll
    for (int j = 0; j < 4; ++j) acc[ci][j] = 0.f;

  const float* sbase = spa + b * L * L;
  const float* r0 = sbase + tp * L;
  const float* r1 = sbase + (tp + 64) * L;
  const float* r2 = sbase + (tp + 128) * L;
  const float* r3 = sbase + (tp + 192) * L;
  const bool ok3 = (tp + 192) < L;

  for (int q = 0; q < L; ++q) {
    float sp0 = r0[q], sp1 = r1[q], sp2 = r2[q], sp3 = ok3 ? r3[q] : 0.f;
#pragma unroll
    for (int ci = 0; ci < 16; ++ci) {
      float vv = fsh[tc * 16 + ci][q];
      acc[ci][0] += vv * sp0;
      acc[ci][1] += vv * sp1;
      acc[ci][2] += vv * sp2;
      acc[ci][3] += vv * sp3;
    }
  }

#pragma unroll
  for (int j = 0; j < 4; ++j) {
    const int p = tp + 64 * j;
    if (p < L) {
      const int pyy = p / NW, pxx = p - pyy * NW;
      const int base =
          (b * CCH + tc * 16) * HW + (pyy * STR + ky) * W + pxx * STR + kx;
#pragma unroll
      for (int ci = 0; ci < 16; ++ci)
        atomicAdd(&x[base + ci * HW], acc[ci][j]);
    }
  }
}

// ---------------------------------------------------------------------------
// Kernel C: spectral residual + gated fusion (unchanged).
// ---------------------------------------------------------------------------
__global__ __launch_bounds__(256) void final_k(
    const float* __restrict__ f, const float* __restrict__ spe,
    const float* __restrict__ Wl, const float* __restrict__ bl,
    float* __restrict__ xo) {
  const int b = blockIdx.y;
  const int n = blockIdx.x * 256 + threadIdx.x;
  const int pb = b * CCH * HW + n;
  const float* sp = spe + b * CCH * CCH;

  float res[CCH];
#pragma unroll
  for (int c = 0; c < CCH; ++c) res[c] = 0.f;

  for (int dc = 0; dc < 4; ++dc) {
    float vf[16];
#pragma unroll
    for (int dd = 0; dd < 16; ++dd) vf[dd] = f[pb + (dc * 16 + dd) * HW];
#pragma unroll
    for (int c = 0; c < CCH; ++c) {
      float a = res[c];
      const float* sr = sp + c * CCH + dc * 16;
#pragma unroll
      for (int dd = 0; dd < 16; ++dd) a += sr[dd] * vf[dd];
      res[c] = a;
    }
  }

  float xa[CCH];
#pragma unroll
  for (int c = 0; c < CCH; ++c) xa[c] = 0.5f * (xo[pb + c * HW] + res[c]);

#pragma unroll 4
  for (int c = 0; c < CCH; ++c) {
    float t = bl[c];
    const float* wr = Wl + c * CCH;
#pragma unroll
    for (int j = 0; j < CCH; ++j) t += wr[j] * xa[j];
    t = lrelu(t);
    const float wei = 1.f / (1.f + __expf(-t));
    const float xv = 2.f * xa[c] - res[c];
    xo[pb + c * HW] = xv * wei + res[c] * (1.f - wei) + f[pb + c * HW];
  }
}

// ---------------------------------------------------------------------------
extern "C" void kernel_launch(void* const* d_in, const int* in_sizes, int n_in,
                              void* d_out, int out_size, void* d_ws,
                              size_t ws_size, hipStream_t stream) {
  const float* fea = (const float*)d_in[0];
  const float* spa = (const float*)d_in[1];
  const float* spe = (const float*)d_in[2];
  const float* W1  = (const float*)d_in[3];
  const float* W2  = (const float*)d_in[4];
  const float* Wl  = (const float*)d_in[5];
  const float* bl  = (const float*)d_in[6];
  float* out = (float*)d_out;

  const size_t F_BYTES   = (size_t)BT * CCH * HW * 4;   // 64 MB fp32 f
  const size_t FBF_BYTES = (size_t)BT * CCH * HW * 2;   // 32 MB bf16 f
  const size_t SPA_BYTES = (size_t)BT * PN * PK * 2;    // ~2 MB bf16 spa
  const size_t NEED = F_BYTES + FBF_BYTES + SPA_BYTES;

  float* f = (float*)d_ws;

  if (ws_size >= NEED) {
    __hip_bfloat16* fbf = (__hip_bfloat16*)((char*)d_ws + F_BYTES);
    __hip_bfloat16* spa_bf = (__hip_bfloat16*)((char*)d_ws + F_BYTES + FBF_BYTES);
    spa_prep_k<<<dim3(BT * PN * PK / 256), 256, 0, stream>>>(spa, spa_bf);
    basic_block_k<<<dim3(8, 8, BT), 256, 0, stream>>>(fea, W1, W2, f, fbf);
    spa_mfma_k<<<dim3(BT * 64), 512, 0, stream>>>(fbf, spa_bf, out);
  } else {
    hipMemsetAsync(d_out, 0, (size_t)out_size * sizeof(float), stream);
    basic_block_k<<<dim3(8, 8, BT), 256, 0, stream>>>(fea, W1, W2, f, nullptr);
    spa_fold_k<<<dim3(KS, KS, BT), 256, 0, stream>>>(f, spa, out);
  }
  final_k<<<dim3(HW / 256, BT), 256, 0, stream>>>(f, spe, Wl, bl, out);
}

// Round 4
// 657.972 us; speedup vs baseline: 4.1824x; 1.3071x over previous
//
#include <hip/hip_runtime.h>
#include <hip/hip_bf16.h>
#include <hip/hip_runtime_api.h>

#define BT 16
#define CCH 64
#define H 128
#define W 128
#define STR 8
#define NH 15
#define NW 15
#define L 225
#define HW (H * W)

// spa_bf padded geometry
#define PN 240
#define PK 256
#define APITCH 264
#define GPITCH 260

// conv LDS pitches (elements)
#define CP 72   // fea halo tile channel pitch: px stride 144B (16B-mult), minimal b128 bank spread
#define MP 40   // mid repack pitch: px stride 80B

typedef __attribute__((ext_vector_type(8))) short short8;
typedef __attribute__((ext_vector_type(4))) float f32x4;
typedef __attribute__((ext_vector_type(4))) unsigned short ushort4_t;

__device__ __forceinline__ float lrelu(float v) { return v > 0.f ? v : 0.2f * v; }
__device__ __forceinline__ unsigned short f2bf(float v) {
  __hip_bfloat16 h = __float2bfloat16(v);
  unsigned short u;
  __builtin_memcpy(&u, &h, 2);
  return u;
}

// ---------------------------------------------------------------------------
// Prep: weights -> MFMA fragment order, bf16.
// W1r[((pos*2+s)*32 + mc)*32 + ck] = W1[mc][s*32+ck][pos/3][pos%3]
// W2r[oc*32+mc] = W2[oc][mc]
// ---------------------------------------------------------------------------
__global__ __launch_bounds__(256) void prep_w_k(
    const float* __restrict__ W1, const float* __restrict__ W2,
    __hip_bfloat16* __restrict__ W1r, __hip_bfloat16* __restrict__ W2r) {
  const int tid = threadIdx.x;
  for (int idx = tid; idx < 18432; idx += 256) {
    const int kk = idx >> 10, mc = (idx >> 5) & 31, ck = idx & 31;
    const int pos = kk >> 1, s = kk & 1;
    W1r[idx] = __float2bfloat16(W1[(mc * 64 + s * 32 + ck) * 9 + pos]);
  }
  for (int idx = tid; idx < 2048; idx += 256)
    W2r[idx] = __float2bfloat16(W2[idx]);
}

// ---------------------------------------------------------------------------
// Prep: fea NCHW fp32 -> fea_t NHWC bf16. Thread packs 8 channels of one
// pixel (8 strided scalar reads, one 16B store -> perfectly coalesced writes).
// ---------------------------------------------------------------------------
__global__ __launch_bounds__(256) void fea_t_k(
    const float* __restrict__ fea, __hip_bfloat16* __restrict__ ft) {
  const int b = blockIdx.y;
  const int p0 = blockIdx.x * 256;
  const int tid = threadIdx.x;
#pragma unroll 1
  for (int it = 0; it < 8; ++it) {
    const int u = it * 256 + tid;
    const int px = u >> 3, g = u & 7;
    const int p = p0 + px;
    short8 v;
#pragma unroll
    for (int j = 0; j < 8; ++j)
      v[j] = (short)f2bf(fea[((size_t)b * CCH + g * 8 + j) * HW + p]);
    *(short8*)&ft[((size_t)b * HW + p) * CCH + g * 8] = v;
  }
}

// ---------------------------------------------------------------------------
// Prep: spa fp32 [b][225][225] -> spa_bf bf16 [b][240][256] zero-padded.
// ---------------------------------------------------------------------------
__global__ __launch_bounds__(256) void spa_prep_k(
    const float* __restrict__ spa, __hip_bfloat16* __restrict__ spa_bf) {
  const int idx = blockIdx.x * 256 + threadIdx.x;
  const int b = idx / (PN * PK);
  const int r = idx - b * (PN * PK);
  const int p = r >> 8, q = r & 255;
  float v = (p < L && q < L) ? spa[(b * L + p) * L + q] : 0.f;
  spa_bf[idx] = __float2bfloat16(v);
}

// ---------------------------------------------------------------------------
// Kernel A (MFMA): BasicBlock as implicit GEMM.
// Block = (b, 16x16 pixel tile), 512 thr = 8 waves. Stage 18x18x64 bf16 halo
// tile (NHWC, reflect) in LDS. conv3x3: D[32 mid][256 px] via 9 pos x 2
// channel-halves of 16x16x32 MFMA (A = W1r frags from global/L1, B = LDS).
// lrelu -> wave-private LDS repack mid[n][mc] -> 1x1 conv: D2[64 oc][px] via
// 8 MFMA/wave -> lrelu -> bf16 NCHW store. Wave w owns ntiles {2w, 2w+1}.
// ---------------------------------------------------------------------------
__global__ __launch_bounds__(512) void bblock_mfma_k(
    const __hip_bfloat16* __restrict__ ft, const __hip_bfloat16* __restrict__ W1r,
    const __hip_bfloat16* __restrict__ W2r, __hip_bfloat16* __restrict__ fbf) {
  __shared__ __align__(16) short st[324 * CP];    // 46.7 KB
  __shared__ __align__(16) short mids[256 * MP];  // 20 KB
  const int b = blockIdx.z, ty0 = blockIdx.y * 16, tx0 = blockIdx.x * 16;
  const int tid = threadIdx.x;

  for (int i = tid; i < 2592; i += 512) {  // 324 px * 8 ch-groups
    const int px = i >> 3, g = i & 7;
    const int iy = px / 18, ix = px - iy * 18;
    int gy = ty0 + iy - 1;
    gy = gy < 0 ? -gy : (gy > 127 ? 254 - gy : gy);
    int gx = tx0 + ix - 1;
    gx = gx < 0 ? -gx : (gx > 127 ? 254 - gx : gx);
    *(short8*)&st[px * CP + g * 8] =
        *(const short8*)&ft[((size_t)b * HW + gy * W + gx) * CCH + g * 8];
  }
  __syncthreads();

  const int w = tid >> 6, lane = tid & 63, lm = lane & 15, lk = lane >> 4;
  const short* w1 = (const short*)W1r;
  const short* w2 = (const short*)W2r;

  f32x4 acc[2][2];  // [mtile][ntile-of-wave]
#pragma unroll
  for (int mt = 0; mt < 2; ++mt)
#pragma unroll
    for (int t = 0; t < 2; ++t) acc[mt][t] = (f32x4){0.f, 0.f, 0.f, 0.f};

#pragma unroll
  for (int pos = 0; pos < 9; ++pos) {
    const int dy = pos / 3, dx = pos - dy * 3;
#pragma unroll
    for (int s = 0; s < 2; ++s) {
      short8 a0 = *(const short8*)&w1[((pos * 2 + s) * 32 + lm) * 32 + lk * 8];
      short8 a1 = *(const short8*)&w1[((pos * 2 + s) * 32 + 16 + lm) * 32 + lk * 8];
#pragma unroll
      for (int t = 0; t < 2; ++t) {
        const int p = (w * 2 + t + dy) * 18 + lm + dx;  // halo pixel index
        short8 bb = *(const short8*)&st[p * CP + s * 32 + lk * 8];
        acc[0][t] = __builtin_amdgcn_mfma_f32_16x16x32_bf16(a0, bb, acc[0][t], 0, 0, 0);
        acc[1][t] = __builtin_amdgcn_mfma_f32_16x16x32_bf16(a1, bb, acc[1][t], 0, 0, 0);
      }
    }
  }

  // lrelu + repack mid -> LDS [n][mc] (wave-private rows n = 32w..32w+31)
#pragma unroll
  for (int t = 0; t < 2; ++t) {
    const int n = (w * 2 + t) * 16 + lm;
#pragma unroll
    for (int mt = 0; mt < 2; ++mt) {
      ushort4_t pk;
#pragma unroll
      for (int r = 0; r < 4; ++r) pk[r] = f2bf(lrelu(acc[mt][t][r]));
      *(ushort4_t*)&mids[n * MP + mt * 16 + lk * 4] = pk;
    }
  }
  __syncthreads();

  // 1x1 conv: K=32, one MFMA per (oc-tile, ntile)
  f32x4 acc2[4][2];
#pragma unroll
  for (int m2 = 0; m2 < 4; ++m2)
#pragma unroll
    for (int t = 0; t < 2; ++t) acc2[m2][t] = (f32x4){0.f, 0.f, 0.f, 0.f};

  short8 b2[2];
#pragma unroll
  for (int t = 0; t < 2; ++t)
    b2[t] = *(const short8*)&mids[((w * 2 + t) * 16 + lm) * MP + lk * 8];
#pragma unroll
  for (int m2 = 0; m2 < 4; ++m2) {
    short8 a2 = *(const short8*)&w2[(m2 * 16 + lm) * 32 + lk * 8];
#pragma unroll
    for (int t = 0; t < 2; ++t)
      acc2[m2][t] = __builtin_amdgcn_mfma_f32_16x16x32_bf16(a2, b2[t], acc2[m2][t], 0, 0, 0);
  }

  // lrelu + store bf16 NCHW: oc = m2*16+lk*4+r, pixel (ty0 + 2w+t, tx0 + lm)
  unsigned short* fo = (unsigned short*)fbf;
#pragma unroll
  for (int m2 = 0; m2 < 4; ++m2)
#pragma unroll
    for (int t = 0; t < 2; ++t) {
      const int y = ty0 + w * 2 + t, x = tx0 + lm;
#pragma unroll
      for (int r = 0; r < 4; ++r) {
        const int oc = m2 * 16 + lk * 4 + r;
        fo[((size_t)(b * CCH + oc)) * HW + y * W + x] = f2bf(lrelu(acc2[m2][t][r]));
      }
    }
}

// ---------------------------------------------------------------------------
// Kernel B (MFMA): spatial-graph matmul + fused fold (unchanged from R3).
// ---------------------------------------------------------------------------
__global__ __launch_bounds__(512) void spa_mfma_k(
    const __hip_bfloat16* __restrict__ fbf,
    const __hip_bfloat16* __restrict__ spa_bf, float* __restrict__ x) {
  __shared__ __align__(16) short fs[CCH * APITCH];
  __shared__ __align__(16) float gout[CCH * GPITCH];

  const int lb = ((int)blockIdx.x % 8) * 128 + (int)blockIdx.x / 8;
  const int b = lb >> 6, ky0 = (lb >> 3) & 7, kx0 = lb & 7;
  const int tid = threadIdx.x;

  for (int i = tid; i < CCH * GPITCH; i += 512) gout[i] = 0.f;

  const int w = tid >> 6, lane = tid & 63;
  const int lm = lane & 15, lk = lane >> 4;
  const int mt0 = (w >> 2) * 2;
  const int nt0 = (w & 3) * 4;
  const int nnt = ((w & 3) == 3) ? 3 : 4;

  const unsigned short* fb = (const unsigned short*)fbf + (size_t)b * CCH * HW;
  const short* sb = (const short*)spa_bf + (size_t)b * PN * PK;

#pragma unroll 1
  for (int v = 0; v < 4; ++v) {
    const int vy = v >> 1, vx = v & 1;
    const int ky = ky0 + 8 * vy, kx = kx0 + 8 * vx;

    __syncthreads();
    for (int i = tid; i < CCH * 256; i += 512) {
      const int c = i >> 8, q = i & 255;
      short val = 0;
      if (q < L) {
        const int qy = q / NW, qx = q - qy * NW;
        val = (short)fb[(c * H + qy * STR + ky) * W + qx * STR + kx];
      }
      fs[c * APITCH + q] = val;
    }
    __syncthreads();

    f32x4 acc[2][4];
#pragma unroll
    for (int mi = 0; mi < 2; ++mi)
#pragma unroll
      for (int n = 0; n < 4; ++n) acc[mi][n] = (f32x4){0.f, 0.f, 0.f, 0.f};

#pragma unroll 1
    for (int K0 = 0; K0 < PK; K0 += 32) {
      const int ko = K0 + 8 * lk;
      short8 a0 = *(const short8*)&fs[(mt0 * 16 + lm) * APITCH + ko];
      short8 a1 = *(const short8*)&fs[((mt0 + 1) * 16 + lm) * APITCH + ko];
#pragma unroll
      for (int n = 0; n < 4; ++n) {
        if (n < nnt) {
          short8 bb = *(const short8*)&sb[((nt0 + n) * 16 + lm) * PK + ko];
          acc[0][n] = __builtin_amdgcn_mfma_f32_16x16x32_bf16(a0, bb, acc[0][n], 0, 0, 0);
          acc[1][n] = __builtin_amdgcn_mfma_f32_16x16x32_bf16(a1, bb, acc[1][n], 0, 0, 0);
        }
      }
    }

#pragma unroll
    for (int mi = 0; mi < 2; ++mi) {
#pragma unroll
      for (int n = 0; n < 4; ++n) {
        if (n >= nnt) continue;
        const int p = (nt0 + n) * 16 + lm;
        if (p >= L) continue;
        const int qy = p / NW, qx = p - qy * NW;
        const int yi = qy + vy, xi = qx + vx;
        float* g = &gout[((mt0 + mi) * 16 + lk * 4) * GPITCH + yi * 16 + xi];
#pragma unroll
        for (int r = 0; r < 4; ++r) g[r * GPITCH] += acc[mi][n][r];
      }
    }
  }

  __syncthreads();
  float* xb = x + (size_t)b * CCH * HW;
  for (int i = tid; i < CCH * 256; i += 512) {
    const int c = i >> 8, yi = (i >> 4) & 15, xi = i & 15;
    xb[(c * H + yi * STR + ky0) * W + xi * STR + kx0] =
        gout[c * GPITCH + yi * 16 + xi];
  }
}

// ---------------------------------------------------------------------------
// Kernel C: spectral residual + gated fusion; f is now bf16.
// ---------------------------------------------------------------------------
__global__ __launch_bounds__(256) void final_k(
    const __hip_bfloat16* __restrict__ fbf, const float* __restrict__ spe,
    const float* __restrict__ Wl, const float* __restrict__ bl,
    float* __restrict__ xo) {
  const int b = blockIdx.y;
  const int n = blockIdx.x * 256 + threadIdx.x;
  const size_t pb = (size_t)b * CCH * HW + n;
  const float* sp = spe + b * CCH * CCH;

  float fv[CCH];
#pragma unroll
  for (int c = 0; c < CCH; ++c) fv[c] = __bfloat162float(fbf[pb + c * HW]);

  float res[CCH];
#pragma unroll
  for (int c = 0; c < CCH; ++c) res[c] = 0.f;

#pragma unroll 4
  for (int c = 0; c < CCH; ++c) {
    float a = 0.f;
    const float* sr = sp + c * CCH;
#pragma unroll
    for (int dd = 0; dd < CCH; ++dd) a += sr[dd] * fv[dd];
    res[c] = a;
  }

  float xa[CCH];
#pragma unroll
  for (int c = 0; c < CCH; ++c) xa[c] = 0.5f * (xo[pb + c * HW] + res[c]);

#pragma unroll 4
  for (int c = 0; c < CCH; ++c) {
    float t = bl[c];
    const float* wr = Wl + c * CCH;
#pragma unroll
    for (int j = 0; j < CCH; ++j) t += wr[j] * xa[j];
    t = lrelu(t);
    const float wei = 1.f / (1.f + __expf(-t));
    const float xv = 2.f * xa[c] - res[c];
    xo[pb + c * HW] = xv * wei + res[c] * (1.f - wei) + fv[c];
  }
}

// ---------------------------------------------------------------------------
extern "C" void kernel_launch(void* const* d_in, const int* in_sizes, int n_in,
                              void* d_out, int out_size, void* d_ws,
                              size_t ws_size, hipStream_t stream) {
  const float* fea = (const float*)d_in[0];
  const float* spa = (const float*)d_in[1];
  const float* spe = (const float*)d_in[2];
  const float* W1  = (const float*)d_in[3];
  const float* W2  = (const float*)d_in[4];
  const float* Wl  = (const float*)d_in[5];
  const float* bl  = (const float*)d_in[6];
  float* out = (float*)d_out;

  // ws layout (all 16B-aligned offsets)
  const size_t FBF_BYTES = (size_t)BT * CCH * HW * 2;  // 32 MB
  const size_t SPA_BYTES = (size_t)BT * PN * PK * 2;   // ~2 MB
  const size_t FT_BYTES  = (size_t)BT * HW * CCH * 2;  // 32 MB
  char* wsb = (char*)d_ws;
  __hip_bfloat16* fbf    = (__hip_bfloat16*)wsb;
  __hip_bfloat16* spa_bf = (__hip_bfloat16*)(wsb + FBF_BYTES);
  __hip_bfloat16* ft     = (__hip_bfloat16*)(wsb + FBF_BYTES + SPA_BYTES);
  __hip_bfloat16* W1r    = (__hip_bfloat16*)(wsb + FBF_BYTES + SPA_BYTES + FT_BYTES);
  __hip_bfloat16* W2r    = W1r + 18432;

  prep_w_k<<<dim3(1), 256, 0, stream>>>(W1, W2, W1r, W2r);
  fea_t_k<<<dim3(HW / 256, BT), 256, 0, stream>>>(fea, ft);
  spa_prep_k<<<dim3(BT * PN * PK / 256), 256, 0, stream>>>(spa, spa_bf);
  bblock_mfma_k<<<dim3(8, 8, BT), 512, 0, stream>>>(ft, W1r, W2r, fbf);
  spa_mfma_k<<<dim3(BT * 64), 512, 0, stream>>>(fbf, spa_bf, out);
  final_k<<<dim3(HW / 256, BT), 256, 0, stream>>>(fbf, spe, Wl, bl, out);
}

// Round 5
// 361.460 us; speedup vs baseline: 7.6134x; 1.8203x over previous
//
#include <hip/hip_runtime.h>
#include <hip/hip_bf16.h>
#include <hip/hip_runtime_api.h>

#define BT 16
#define CCH 64
#define H 128
#define W 128
#define STR 8
#define NH 15
#define NW 15
#define L 225
#define HW (H * W)

// spa_bf padded geometry
#define PN 240
#define PK 256
#define APITCH 264
#define GPITCH 260

// conv LDS pitches (elements)
#define CP 72   // halo tile channel pitch (bblock) and final-stage row pitch
#define MP 40   // mid repack pitch

typedef __attribute__((ext_vector_type(8))) short short8;
typedef __attribute__((ext_vector_type(4))) float f32x4;
typedef __attribute__((ext_vector_type(4))) unsigned short ushort4_t;

__device__ __forceinline__ float lrelu(float v) { return v > 0.f ? v : 0.2f * v; }
__device__ __forceinline__ unsigned short f2bf(float v) {
  __hip_bfloat16 h = __float2bfloat16(v);
  unsigned short u;
  __builtin_memcpy(&u, &h, 2);
  return u;
}
__device__ __forceinline__ float bf2f(unsigned short u) {
  unsigned int x = ((unsigned int)u) << 16;
  float f;
  __builtin_memcpy(&f, &x, 4);
  return f;
}

// ---------------------------------------------------------------------------
// Prep (one kernel, grid-strided ranges):
//  W1r[((pos*2+s)*32+mc)*32+ck] = W1[mc][s*32+ck][pos]   (bf16)
//  W2r[oc*32+mc] = W2[oc][mc]                            (bf16)
//  spe_r = bf16(spe) row-major (already fragment order)
//  wl_r  = bf16(Wl)  row-major
// ---------------------------------------------------------------------------
__global__ __launch_bounds__(256) void prep_w_k(
    const float* __restrict__ W1, const float* __restrict__ W2,
    const float* __restrict__ spe, const float* __restrict__ Wl,
    __hip_bfloat16* __restrict__ W1r, __hip_bfloat16* __restrict__ W2r,
    __hip_bfloat16* __restrict__ spe_r, __hip_bfloat16* __restrict__ wl_r) {
  const int idx = blockIdx.x * 256 + threadIdx.x;
  if (idx < 18432) {
    const int kk = idx >> 10, mc = (idx >> 5) & 31, ck = idx & 31;
    const int pos = kk >> 1, s = kk & 1;
    W1r[idx] = __float2bfloat16(W1[(mc * 64 + s * 32 + ck) * 9 + pos]);
    return;
  }
  int i = idx - 18432;
  if (i < 2048) { W2r[i] = __float2bfloat16(W2[i]); return; }
  i -= 2048;
  if (i < BT * CCH * CCH) { spe_r[i] = __float2bfloat16(spe[i]); return; }
  i -= BT * CCH * CCH;
  if (i < CCH * CCH) { wl_r[i] = __float2bfloat16(Wl[i]); return; }
}

// ---------------------------------------------------------------------------
// Prep: fea NCHW fp32 -> ft NHWC bf16.
// ---------------------------------------------------------------------------
__global__ __launch_bounds__(256) void fea_t_k(
    const float* __restrict__ fea, __hip_bfloat16* __restrict__ ft) {
  const int b = blockIdx.y;
  const int p0 = blockIdx.x * 256;
  const int tid = threadIdx.x;
#pragma unroll 1
  for (int it = 0; it < 8; ++it) {
    const int u = it * 256 + tid;
    const int px = u >> 3, g = u & 7;
    const int p = p0 + px;
    short8 v;
#pragma unroll
    for (int j = 0; j < 8; ++j)
      v[j] = (short)f2bf(fea[((size_t)b * CCH + g * 8 + j) * HW + p]);
    *(short8*)&ft[((size_t)b * HW + p) * CCH + g * 8] = v;
  }
}

// ---------------------------------------------------------------------------
// Prep: spa fp32 [b][225][225] -> spa_bf bf16 [b][240][256] zero-padded.
// ---------------------------------------------------------------------------
__global__ __launch_bounds__(256) void spa_prep_k(
    const float* __restrict__ spa, __hip_bfloat16* __restrict__ spa_bf) {
  const int idx = blockIdx.x * 256 + threadIdx.x;
  const int b = idx / (PN * PK);
  const int r = idx - b * (PN * PK);
  const int p = r >> 8, q = r & 255;
  float v = (p < L && q < L) ? spa[(b * L + p) * L + q] : 0.f;
  spa_bf[idx] = __float2bfloat16(v);
}

// ---------------------------------------------------------------------------
// Kernel A (MFMA): BasicBlock implicit GEMM. Output: fnh NHWC bf16 only.
// 512 thr = 8 waves; wave w owns tile rows {2w, 2w+1}.
// ---------------------------------------------------------------------------
__global__ __launch_bounds__(512) void bblock_mfma_k(
    const __hip_bfloat16* __restrict__ ft, const __hip_bfloat16* __restrict__ W1r,
    const __hip_bfloat16* __restrict__ W2r, __hip_bfloat16* __restrict__ fnh) {
  __shared__ __align__(16) short st[324 * CP];    // 46.7 KB
  __shared__ __align__(16) short mids[256 * MP];  // 20 KB
  const int b = blockIdx.z, ty0 = blockIdx.y * 16, tx0 = blockIdx.x * 16;
  const int tid = threadIdx.x;

  for (int i = tid; i < 2592; i += 512) {  // 324 px * 8 ch-groups
    const int px = i >> 3, g = i & 7;
    const int iy = px / 18, ix = px - iy * 18;
    int gy = ty0 + iy - 1;
    gy = gy < 0 ? -gy : (gy > 127 ? 254 - gy : gy);
    int gx = tx0 + ix - 1;
    gx = gx < 0 ? -gx : (gx > 127 ? 254 - gx : gx);
    *(short8*)&st[px * CP + g * 8] =
        *(const short8*)&ft[((size_t)b * HW + gy * W + gx) * CCH + g * 8];
  }
  __syncthreads();

  const int w = tid >> 6, lane = tid & 63, lm = lane & 15, lk = lane >> 4;
  const short* w1 = (const short*)W1r;
  const short* w2 = (const short*)W2r;

  f32x4 acc[2][2];
#pragma unroll
  for (int mt = 0; mt < 2; ++mt)
#pragma unroll
    for (int t = 0; t < 2; ++t) acc[mt][t] = (f32x4){0.f, 0.f, 0.f, 0.f};

#pragma unroll
  for (int pos = 0; pos < 9; ++pos) {
    const int dy = pos / 3, dx = pos - dy * 3;
#pragma unroll
    for (int s = 0; s < 2; ++s) {
      short8 a0 = *(const short8*)&w1[((pos * 2 + s) * 32 + lm) * 32 + lk * 8];
      short8 a1 = *(const short8*)&w1[((pos * 2 + s) * 32 + 16 + lm) * 32 + lk * 8];
#pragma unroll
      for (int t = 0; t < 2; ++t) {
        const int p = (w * 2 + t + dy) * 18 + lm + dx;
        short8 bb = *(const short8*)&st[p * CP + s * 32 + lk * 8];
        acc[0][t] = __builtin_amdgcn_mfma_f32_16x16x32_bf16(a0, bb, acc[0][t], 0, 0, 0);
        acc[1][t] = __builtin_amdgcn_mfma_f32_16x16x32_bf16(a1, bb, acc[1][t], 0, 0, 0);
      }
    }
  }

  // lrelu + repack mid -> LDS [n][mc] (wave-private rows)
#pragma unroll
  for (int t = 0; t < 2; ++t) {
    const int n = (w * 2 + t) * 16 + lm;
#pragma unroll
    for (int mt = 0; mt < 2; ++mt) {
      ushort4_t pk;
#pragma unroll
      for (int r = 0; r < 4; ++r) pk[r] = f2bf(lrelu(acc[mt][t][r]));
      *(ushort4_t*)&mids[n * MP + mt * 16 + lk * 4] = pk;
    }
  }
  __syncthreads();

  f32x4 acc2[4][2];
#pragma unroll
  for (int m2 = 0; m2 < 4; ++m2)
#pragma unroll
    for (int t = 0; t < 2; ++t) acc2[m2][t] = (f32x4){0.f, 0.f, 0.f, 0.f};

  short8 b2[2];
#pragma unroll
  for (int t = 0; t < 2; ++t)
    b2[t] = *(const short8*)&mids[((w * 2 + t) * 16 + lm) * MP + lk * 8];
#pragma unroll
  for (int m2 = 0; m2 < 4; ++m2) {
    short8 a2 = *(const short8*)&w2[(m2 * 16 + lm) * 32 + lk * 8];
#pragma unroll
    for (int t = 0; t < 2; ++t)
      acc2[m2][t] = __builtin_amdgcn_mfma_f32_16x16x32_bf16(a2, b2[t], acc2[m2][t], 0, 0, 0);
  }

  // lrelu + store NHWC bf16: 4 consecutive oc per 8B store
  unsigned short* fo = (unsigned short*)fnh;
#pragma unroll
  for (int m2 = 0; m2 < 4; ++m2)
#pragma unroll
    for (int t = 0; t < 2; ++t) {
      const int y = ty0 + w * 2 + t, x = tx0 + lm;
      ushort4_t pk;
#pragma unroll
      for (int r = 0; r < 4; ++r) pk[r] = f2bf(lrelu(acc2[m2][t][r]));
      *(ushort4_t*)&fo[((size_t)b * HW + y * W + x) * CCH + m2 * 16 + lk * 4] = pk;
    }
}

// ---------------------------------------------------------------------------
// Kernel B (MFMA): spatial-graph matmul + fused fold. f source is now NHWC:
// staging loop is c-fast (coalesced 128B global reads per wave).
// ---------------------------------------------------------------------------
__global__ __launch_bounds__(512) void spa_mfma_k(
    const __hip_bfloat16* __restrict__ fnh,
    const __hip_bfloat16* __restrict__ spa_bf, float* __restrict__ x) {
  __shared__ __align__(16) short fs[CCH * APITCH];
  __shared__ __align__(16) float gout[CCH * GPITCH];

  const int lb = ((int)blockIdx.x % 8) * 128 + (int)blockIdx.x / 8;
  const int b = lb >> 6, ky0 = (lb >> 3) & 7, kx0 = lb & 7;
  const int tid = threadIdx.x;

  for (int i = tid; i < CCH * GPITCH; i += 512) gout[i] = 0.f;

  const int w = tid >> 6, lane = tid & 63;
  const int lm = lane & 15, lk = lane >> 4;
  const int mt0 = (w >> 2) * 2;
  const int nt0 = (w & 3) * 4;
  const int nnt = ((w & 3) == 3) ? 3 : 4;

  const unsigned short* fb = (const unsigned short*)fnh + (size_t)b * HW * CCH;
  const short* sb = (const short*)spa_bf + (size_t)b * PN * PK;

#pragma unroll 1
  for (int v = 0; v < 4; ++v) {
    const int vy = v >> 1, vx = v & 1;
    const int ky = ky0 + 8 * vy, kx = kx0 + 8 * vx;

    __syncthreads();
    for (int i = tid; i < CCH * 256; i += 512) {
      const int q = i >> 6, c = i & 63;   // c-fast: coalesced global reads
      short val = 0;
      if (q < L) {
        const int qy = q / NW, qx = q - qy * NW;
        val = (short)fb[((qy * STR + ky) * W + qx * STR + kx) * CCH + c];
      }
      fs[c * APITCH + q] = val;
    }
    __syncthreads();

    f32x4 acc[2][4];
#pragma unroll
    for (int mi = 0; mi < 2; ++mi)
#pragma unroll
      for (int n = 0; n < 4; ++n) acc[mi][n] = (f32x4){0.f, 0.f, 0.f, 0.f};

#pragma unroll 1
    for (int K0 = 0; K0 < PK; K0 += 32) {
      const int ko = K0 + 8 * lk;
      short8 a0 = *(const short8*)&fs[(mt0 * 16 + lm) * APITCH + ko];
      short8 a1 = *(const short8*)&fs[((mt0 + 1) * 16 + lm) * APITCH + ko];
#pragma unroll
      for (int n = 0; n < 4; ++n) {
        if (n < nnt) {
          short8 bb = *(const short8*)&sb[((nt0 + n) * 16 + lm) * PK + ko];
          acc[0][n] = __builtin_amdgcn_mfma_f32_16x16x32_bf16(a0, bb, acc[0][n], 0, 0, 0);
          acc[1][n] = __builtin_amdgcn_mfma_f32_16x16x32_bf16(a1, bb, acc[1][n], 0, 0, 0);
        }
      }
    }

#pragma unroll
    for (int mi = 0; mi < 2; ++mi) {
#pragma unroll
      for (int n = 0; n < 4; ++n) {
        if (n >= nnt) continue;
        const int p = (nt0 + n) * 16 + lm;
        if (p >= L) continue;
        const int qy = p / NW, qx = p - qy * NW;
        const int yi = qy + vy, xi = qx + vx;
        float* g = &gout[((mt0 + mi) * 16 + lk * 4) * GPITCH + yi * 16 + xi];
#pragma unroll
        for (int r = 0; r < 4; ++r) g[r * GPITCH] += acc[mi][n][r];
      }
    }
  }

  __syncthreads();
  float* xb = x + (size_t)b * CCH * HW;
  for (int i = tid; i < CCH * 256; i += 512) {
    const int c = i >> 8, yi = (i >> 4) & 15, xi = i & 15;
    xb[(c * H + yi * STR + ky0) * W + xi * STR + kx0] =
        gout[c * GPITCH + yi * 16 + xi];
  }
}

// ---------------------------------------------------------------------------
// Kernel C (MFMA): spectral residual + gated fusion.
// Block = 256 thr (4 waves), 128 pixels of one batch. Wave w -> channel
// mtile w. Stage f[px][c] in LDS; res = spe@f (MFMA); xa = 0.5(x+res) kept
// in regs + packed bf16 to xa_lds[px][c]; xl = Wl@xa (MFMA); gate; out.
// out = 2*xa*wei + res*(1-2*wei) + f. In-place on xo; blocks own disjoint px.
// ---------------------------------------------------------------------------
__global__ __launch_bounds__(256) void final_mfma_k(
    const __hip_bfloat16* __restrict__ fnh, const __hip_bfloat16* __restrict__ spe_r,
    const __hip_bfloat16* __restrict__ wl_r, const float* __restrict__ bl,
    float* __restrict__ xo) {
  __shared__ __align__(16) short fl[128 * CP];   // 18.4 KB
  __shared__ __align__(16) short xal[128 * CP];  // 18.4 KB
  const int b = blockIdx.y;
  const int px0 = blockIdx.x * 128;
  const int tid = threadIdx.x;

  for (int i = tid; i < 128 * 8; i += 256) {
    const int px = i >> 3, g = i & 7;
    *(short8*)&fl[px * CP + g * 8] =
        *(const short8*)&fnh[((size_t)b * HW + px0 + px) * CCH + g * 8];
  }
  __syncthreads();

  const int w = tid >> 6, lane = tid & 63, lm = lane & 15, lk = lane >> 4;
  const int c0 = w * 16 + lk * 4;

  // stage 1: res = spe @ f
  const short* sa = (const short*)spe_r + ((size_t)b * CCH + w * 16 + lm) * CCH;
  const short8 a1_0 = *(const short8*)&sa[lk * 8];
  const short8 a1_1 = *(const short8*)&sa[32 + lk * 8];

  f32x4 res[8];
  f32x4 xar[8];
#pragma unroll
  for (int nt = 0; nt < 8; ++nt) {
    const int prow = (nt * 16 + lm) * CP;
    short8 b0 = *(const short8*)&fl[prow + lk * 8];
    short8 b1 = *(const short8*)&fl[prow + 32 + lk * 8];
    f32x4 r = (f32x4){0.f, 0.f, 0.f, 0.f};
    r = __builtin_amdgcn_mfma_f32_16x16x32_bf16(a1_0, b0, r, 0, 0, 0);
    r = __builtin_amdgcn_mfma_f32_16x16x32_bf16(a1_1, b1, r, 0, 0, 0);
    res[nt] = r;
    ushort4_t pk;
    f32x4 xa;
#pragma unroll
    for (int j = 0; j < 4; ++j) {
      const float xv = xo[((size_t)b * CCH + c0 + j) * HW + px0 + nt * 16 + lm];
      xa[j] = 0.5f * (xv + r[j]);
      pk[j] = f2bf(xa[j]);
    }
    xar[nt] = xa;
    *(ushort4_t*)&xal[(nt * 16 + lm) * CP + c0] = pk;
  }
  __syncthreads();

  // stage 2: xl = Wl @ xa; gate; combine
  const short* wa = (const short*)wl_r + (w * 16 + lm) * CCH;
  const short8 a2_0 = *(const short8*)&wa[lk * 8];
  const short8 a2_1 = *(const short8*)&wa[32 + lk * 8];
  float blv[4];
#pragma unroll
  for (int j = 0; j < 4; ++j) blv[j] = bl[c0 + j];

#pragma unroll
  for (int nt = 0; nt < 8; ++nt) {
    const int prow = (nt * 16 + lm) * CP;
    short8 b0 = *(const short8*)&xal[prow + lk * 8];
    short8 b1 = *(const short8*)&xal[prow + 32 + lk * 8];
    f32x4 t = (f32x4){0.f, 0.f, 0.f, 0.f};
    t = __builtin_amdgcn_mfma_f32_16x16x32_bf16(a2_0, b0, t, 0, 0, 0);
    t = __builtin_amdgcn_mfma_f32_16x16x32_bf16(a2_1, b1, t, 0, 0, 0);
    ushort4_t fpk = *(const ushort4_t*)&fl[prow + c0];
#pragma unroll
    for (int j = 0; j < 4; ++j) {
      const float xl = lrelu(t[j] + blv[j]);
      const float wei = 1.f / (1.f + __expf(-xl));
      const float o = 2.f * xar[nt][j] * wei + res[nt][j] * (1.f - 2.f * wei) +
                      bf2f(fpk[j]);
      xo[((size_t)b * CCH + c0 + j) * HW + px0 + nt * 16 + lm] = o;
    }
  }
}

// ---------------------------------------------------------------------------
extern "C" void kernel_launch(void* const* d_in, const int* in_sizes, int n_in,
                              void* d_out, int out_size, void* d_ws,
                              size_t ws_size, hipStream_t stream) {
  const float* fea = (const float*)d_in[0];
  const float* spa = (const float*)d_in[1];
  const float* spe = (const float*)d_in[2];
  const float* W1  = (const float*)d_in[3];
  const float* W2  = (const float*)d_in[4];
  const float* Wl  = (const float*)d_in[5];
  const float* bl  = (const float*)d_in[6];
  float* out = (float*)d_out;

  // ws layout (bytes)
  const size_t SPA_BYTES = (size_t)BT * PN * PK * 2;   // ~2 MB
  const size_t FT_BYTES  = (size_t)BT * HW * CCH * 2;  // 32 MB
  const size_t FNH_BYTES = (size_t)BT * HW * CCH * 2;  // 32 MB
  char* wsb = (char*)d_ws;
  __hip_bfloat16* spa_bf = (__hip_bfloat16*)wsb;
  __hip_bfloat16* ft     = (__hip_bfloat16*)(wsb + SPA_BYTES);
  __hip_bfloat16* fnh    = (__hip_bfloat16*)(wsb + SPA_BYTES + FT_BYTES);
  char* wtb = wsb + SPA_BYTES + FT_BYTES + FNH_BYTES;
  __hip_bfloat16* W1r   = (__hip_bfloat16*)wtb;                    // 18432
  __hip_bfloat16* W2r   = (__hip_bfloat16*)(wtb + 36864);          // 2048
  __hip_bfloat16* spe_r = (__hip_bfloat16*)(wtb + 36864 + 4096);   // 65536
  __hip_bfloat16* wl_r  = (__hip_bfloat16*)(wtb + 36864 + 4096 + 131072);

  prep_w_k<<<dim3(352), 256, 0, stream>>>(W1, W2, spe, Wl, W1r, W2r, spe_r, wl_r);
  fea_t_k<<<dim3(HW / 256, BT), 256, 0, stream>>>(fea, ft);
  spa_prep_k<<<dim3(BT * PN * PK / 256), 256, 0, stream>>>(spa, spa_bf);
  bblock_mfma_k<<<dim3(8, 8, BT), 512, 0, stream>>>(ft, W1r, W2r, fnh);
  spa_mfma_k<<<dim3(BT * 64), 512, 0, stream>>>(fnh, spa_bf, out);
  final_mfma_k<<<dim3(HW / 128, BT), 256, 0, stream>>>(fnh, spe_r, wl_r, bl, out);
}

// Round 6
// 270.501 us; speedup vs baseline: 10.1734x; 1.3363x over previous
//
#include <hip/hip_runtime.h>
#include <hip/hip_bf16.h>
#include <hip/hip_runtime_api.h>

#define BT 16
#define CCH 64
#define H 128
#define W 128
#define STR 8
#define NH 15
#define NW 15
#define L 225
#define HW (H * W)

// spa_shift geometry: p padded to 240, k is 2-D padded (k = qy*16+qx) -> 256
#define PN 240
#define PK 256
// LDS pitches
#define UPITCH 264  // us: bf16 elems per c-row (528B, 16B-mult)
#define GPITCH 260  // gout: floats per c-row
// conv LDS pitches
#define CP 72
#define MP 40

typedef __attribute__((ext_vector_type(8))) short short8;
typedef __attribute__((ext_vector_type(4))) float f32x4;
typedef __attribute__((ext_vector_type(4))) unsigned short ushort4_t;

__device__ __forceinline__ float lrelu(float v) { return v > 0.f ? v : 0.2f * v; }
__device__ __forceinline__ unsigned short f2bf(float v) {
  __hip_bfloat16 h = __float2bfloat16(v);
  unsigned short u;
  __builtin_memcpy(&u, &h, 2);
  return u;
}
__device__ __forceinline__ float bf2f(unsigned short u) {
  unsigned int x = ((unsigned int)u) << 16;
  float f;
  __builtin_memcpy(&f, &x, 4);
  return f;
}

// ---------------------------------------------------------------------------
// Prep: weights -> fragment order bf16 (W1r, W2r); spe/Wl -> bf16 row-major.
// ---------------------------------------------------------------------------
__global__ __launch_bounds__(256) void prep_w_k(
    const float* __restrict__ W1, const float* __restrict__ W2,
    const float* __restrict__ spe, const float* __restrict__ Wl,
    __hip_bfloat16* __restrict__ W1r, __hip_bfloat16* __restrict__ W2r,
    __hip_bfloat16* __restrict__ spe_r, __hip_bfloat16* __restrict__ wl_r) {
  const int idx = blockIdx.x * 256 + threadIdx.x;
  if (idx < 18432) {
    const int kk = idx >> 10, mc = (idx >> 5) & 31, ck = idx & 31;
    const int pos = kk >> 1, s = kk & 1;
    W1r[idx] = __float2bfloat16(W1[(mc * 64 + s * 32 + ck) * 9 + pos]);
    return;
  }
  int i = idx - 18432;
  if (i < 2048) { W2r[i] = __float2bfloat16(W2[i]); return; }
  i -= 2048;
  if (i < BT * CCH * CCH) { spe_r[i] = __float2bfloat16(spe[i]); return; }
  i -= BT * CCH * CCH;
  if (i < CCH * CCH) { wl_r[i] = __float2bfloat16(Wl[i]); return; }
}

// ---------------------------------------------------------------------------
// Prep: fea NCHW fp32 -> ft NHWC bf16.
// ---------------------------------------------------------------------------
__global__ __launch_bounds__(256) void fea_t_k(
    const float* __restrict__ fea, __hip_bfloat16* __restrict__ ft) {
  const int b = blockIdx.y;
  const int p0 = blockIdx.x * 256;
  const int tid = threadIdx.x;
#pragma unroll 1
  for (int it = 0; it < 8; ++it) {
    const int u = it * 256 + tid;
    const int px = u >> 3, g = u & 7;
    const int p = p0 + px;
    short8 v;
#pragma unroll
    for (int j = 0; j < 8; ++j)
      v[j] = (short)f2bf(fea[((size_t)b * CCH + g * 8 + j) * HW + p]);
    *(short8*)&ft[((size_t)b * HW + p) * CCH + g * 8] = v;
  }
}

// ---------------------------------------------------------------------------
// Prep: 4 shifted spa copies, bf16, 2-D padded k.
// ss[((v*BT+b)*PN + p)*PK + k] = spa[b][p][qy*15+qx],
//   qy = (k>>4)-vy, qx = (k&15)-vx (zero when out of range or p>=L).
// ---------------------------------------------------------------------------
__global__ __launch_bounds__(256) void spa_shift_k(
    const float* __restrict__ spa, __hip_bfloat16* __restrict__ ss) {
  const int idx = blockIdx.x * 256 + threadIdx.x;  // 4*BT*PN*PK total
  const int k = idx & 255;
  int t = idx >> 8;
  const int p = t % PN;
  t /= PN;
  const int b = t & 15, v = t >> 4;
  const int vy = v >> 1, vx = v & 1;
  const int qy = (k >> 4) - vy, qx = (k & 15) - vx;
  float val = 0.f;
  if (qy >= 0 && qy < NH && qx >= 0 && qx < NW && p < L)
    val = spa[((size_t)b * L + p) * L + qy * NW + qx];
  ss[idx] = __float2bfloat16(val);
}

// ---------------------------------------------------------------------------
// Kernel A (MFMA): BasicBlock implicit GEMM -> fnh NHWC bf16.
// ---------------------------------------------------------------------------
__global__ __launch_bounds__(512) void bblock_mfma_k(
    const __hip_bfloat16* __restrict__ ft, const __hip_bfloat16* __restrict__ W1r,
    const __hip_bfloat16* __restrict__ W2r, __hip_bfloat16* __restrict__ fnh) {
  __shared__ __align__(16) short st[324 * CP];
  __shared__ __align__(16) short mids[256 * MP];
  const int b = blockIdx.z, ty0 = blockIdx.y * 16, tx0 = blockIdx.x * 16;
  const int tid = threadIdx.x;

  for (int i = tid; i < 2592; i += 512) {
    const int px = i >> 3, g = i & 7;
    const int iy = px / 18, ix = px - iy * 18;
    int gy = ty0 + iy - 1;
    gy = gy < 0 ? -gy : (gy > 127 ? 254 - gy : gy);
    int gx = tx0 + ix - 1;
    gx = gx < 0 ? -gx : (gx > 127 ? 254 - gx : gx);
    *(short8*)&st[px * CP + g * 8] =
        *(const short8*)&ft[((size_t)b * HW + gy * W + gx) * CCH + g * 8];
  }
  __syncthreads();

  const int w = tid >> 6, lane = tid & 63, lm = lane & 15, lk = lane >> 4;
  const short* w1 = (const short*)W1r;
  const short* w2 = (const short*)W2r;

  f32x4 acc[2][2];
#pragma unroll
  for (int mt = 0; mt < 2; ++mt)
#pragma unroll
    for (int t = 0; t < 2; ++t) acc[mt][t] = (f32x4){0.f, 0.f, 0.f, 0.f};

#pragma unroll
  for (int pos = 0; pos < 9; ++pos) {
    const int dy = pos / 3, dx = pos - dy * 3;
#pragma unroll
    for (int s = 0; s < 2; ++s) {
      short8 a0 = *(const short8*)&w1[((pos * 2 + s) * 32 + lm) * 32 + lk * 8];
      short8 a1 = *(const short8*)&w1[((pos * 2 + s) * 32 + 16 + lm) * 32 + lk * 8];
#pragma unroll
      for (int t = 0; t < 2; ++t) {
        const int p = (w * 2 + t + dy) * 18 + lm + dx;
        short8 bb = *(const short8*)&st[p * CP + s * 32 + lk * 8];
        acc[0][t] = __builtin_amdgcn_mfma_f32_16x16x32_bf16(a0, bb, acc[0][t], 0, 0, 0);
        acc[1][t] = __builtin_amdgcn_mfma_f32_16x16x32_bf16(a1, bb, acc[1][t], 0, 0, 0);
      }
    }
  }

#pragma unroll
  for (int t = 0; t < 2; ++t) {
    const int n = (w * 2 + t) * 16 + lm;
#pragma unroll
    for (int mt = 0; mt < 2; ++mt) {
      ushort4_t pk;
#pragma unroll
      for (int r = 0; r < 4; ++r) pk[r] = f2bf(lrelu(acc[mt][t][r]));
      *(ushort4_t*)&mids[n * MP + mt * 16 + lk * 4] = pk;
    }
  }
  __syncthreads();

  f32x4 acc2[4][2];
#pragma unroll
  for (int m2 = 0; m2 < 4; ++m2)
#pragma unroll
    for (int t = 0; t < 2; ++t) acc2[m2][t] = (f32x4){0.f, 0.f, 0.f, 0.f};

  short8 b2[2];
#pragma unroll
  for (int t = 0; t < 2; ++t)
    b2[t] = *(const short8*)&mids[((w * 2 + t) * 16 + lm) * MP + lk * 8];
#pragma unroll
  for (int m2 = 0; m2 < 4; ++m2) {
    short8 a2 = *(const short8*)&w2[(m2 * 16 + lm) * 32 + lk * 8];
#pragma unroll
    for (int t = 0; t < 2; ++t)
      acc2[m2][t] = __builtin_amdgcn_mfma_f32_16x16x32_bf16(a2, b2[t], acc2[m2][t], 0, 0, 0);
  }

  unsigned short* fo = (unsigned short*)fnh;
#pragma unroll
  for (int m2 = 0; m2 < 4; ++m2)
#pragma unroll
    for (int t = 0; t < 2; ++t) {
      const int y = ty0 + w * 2 + t, x = tx0 + lm;
      ushort4_t pk;
#pragma unroll
      for (int r = 0; r < 4; ++r) pk[r] = f2bf(lrelu(acc2[m2][t][r]));
      *(ushort4_t*)&fo[((size_t)b * HW + y * W + x) * CCH + m2 * 16 + lk * 4] = pk;
    }
}

// ---------------------------------------------------------------------------
// Kernel B (MFMA): spatial-graph matmul + fused fold.
// Block = (b,ky0,kx0). ONE A-stage: us[c][k], k = gy*16+gx over the 16x16
// stride-8 pixel grid (ky0+8gy, kx0+8gx). A-frags preloaded to registers
// (shared by all 4 variants; the variant shift lives in spa_shift's B).
// Per variant: MFMA (B streamed from global/L2) + plain-add merge into gout
// at (qy+vy, qx+vx); barrier-separated. Single writeout per output pixel.
// Waves: mtg = w>>2 -> mtiles {2mtg, 2mtg+1}; ntg = w&3 -> ntiles ntg*4..(+4|3).
// ---------------------------------------------------------------------------
__global__ __launch_bounds__(512, 2) void spa_mfma_k(
    const __hip_bfloat16* __restrict__ fnh,
    const __hip_bfloat16* __restrict__ spa_shift, float* __restrict__ x) {
  __shared__ __align__(16) short us[CCH * UPITCH];    // 33.8 KB
  __shared__ __align__(16) float gout[CCH * GPITCH];  // 66.6 KB

  const int lb = ((int)blockIdx.x % 8) * 128 + (int)blockIdx.x / 8;
  const int b = lb >> 6, ky0 = (lb >> 3) & 7, kx0 = lb & 7;
  const int tid = threadIdx.x;

  const unsigned short* fb = (const unsigned short*)fnh + (size_t)b * HW * CCH;

  // stage us once: 16384 elems = 2048 short8 chunks; transpose-write to [c][k]
  for (int i = tid; i < 2048; i += 512) {
    const int pos = i >> 3, g = i & 7;
    const int gy = pos >> 4, gx = pos & 15;
    short8 v = *(const short8*)&fb[((ky0 + 8 * gy) * W + kx0 + 8 * gx) * CCH + g * 8];
#pragma unroll
    for (int e = 0; e < 8; ++e) us[(g * 8 + e) * UPITCH + pos] = v[e];
  }
  // zero gout (disjoint region; no barrier needed before this)
  for (int i = tid; i < CCH * GPITCH; i += 512) gout[i] = 0.f;
  __syncthreads();

  const int w = tid >> 6, lane = tid & 63;
  const int lm = lane & 15, lk = lane >> 4;
  const int mtg = w >> 2, ntg = w & 3;
  const int nt0 = ntg * 4;
  const int nnt = (ntg == 3) ? 3 : 4;

  // A-fragments in registers, reused by all 4 variants
  short8 a[2][8];
#pragma unroll
  for (int mt = 0; mt < 2; ++mt)
#pragma unroll
    for (int k8 = 0; k8 < 8; ++k8)
      a[mt][k8] = *(const short8*)&us[((mtg * 2 + mt) * 16 + lm) * UPITCH + k8 * 32 + lk * 8];

  const short* sbase = (const short*)spa_shift;

#pragma unroll 1
  for (int v = 0; v < 4; ++v) {
    const int vy = v >> 1, vx = v & 1;
    const short* sv = sbase + ((size_t)(v * BT + b) * PN) * PK;

    f32x4 acc[2][4];
#pragma unroll
    for (int mt = 0; mt < 2; ++mt)
#pragma unroll
      for (int n = 0; n < 4; ++n) acc[mt][n] = (f32x4){0.f, 0.f, 0.f, 0.f};

#pragma unroll
    for (int k8 = 0; k8 < 8; ++k8) {
      short8 bb[4];
#pragma unroll
      for (int n = 0; n < 4; ++n)
        if (n < nnt)
          bb[n] = *(const short8*)&sv[((nt0 + n) * 16 + lm) * PK + k8 * 32 + lk * 8];
#pragma unroll
      for (int n = 0; n < 4; ++n) {
        if (n < nnt) {
          acc[0][n] = __builtin_amdgcn_mfma_f32_16x16x32_bf16(a[0][k8], bb[n], acc[0][n], 0, 0, 0);
          acc[1][n] = __builtin_amdgcn_mfma_f32_16x16x32_bf16(a[1][k8], bb[n], acc[1][n], 0, 0, 0);
        }
      }
    }

    // merge into gout: c = (mtg*2+mt)*16 + lk*4 + r; p -> (qy+vy, qx+vx)
#pragma unroll
    for (int mt = 0; mt < 2; ++mt) {
#pragma unroll
      for (int n = 0; n < 4; ++n) {
        if (n >= nnt) continue;
        const int p = (nt0 + n) * 16 + lm;
        if (p >= L) continue;
        const int qy = p / NW, qx = p - qy * NW;
        const int yi = qy + vy, xi = qx + vx;
        float* g = &gout[((mtg * 2 + mt) * 16 + lk * 4) * GPITCH + yi * 16 + xi];
#pragma unroll
        for (int r = 0; r < 4; ++r) g[r * GPITCH] += acc[mt][n][r];
      }
    }
    __syncthreads();  // separate variants' merges (and final merge vs writeout)
  }

  float* xb = x + (size_t)b * CCH * HW;
  for (int i = tid; i < CCH * 256; i += 512) {
    const int c = i >> 8, yi = (i >> 4) & 15, xi = i & 15;
    xb[(c * H + yi * STR + ky0) * W + xi * STR + kx0] =
        gout[c * GPITCH + yi * 16 + xi];
  }
}

// ---------------------------------------------------------------------------
// Kernel C (MFMA): spectral residual + gated fusion (unchanged from R5).
// ---------------------------------------------------------------------------
__global__ __launch_bounds__(256) void final_mfma_k(
    const __hip_bfloat16* __restrict__ fnh, const __hip_bfloat16* __restrict__ spe_r,
    const __hip_bfloat16* __restrict__ wl_r, const float* __restrict__ bl,
    float* __restrict__ xo) {
  __shared__ __align__(16) short fl[128 * CP];
  __shared__ __align__(16) short xal[128 * CP];
  const int b = blockIdx.y;
  const int px0 = blockIdx.x * 128;
  const int tid = threadIdx.x;

  for (int i = tid; i < 128 * 8; i += 256) {
    const int px = i >> 3, g = i & 7;
    *(short8*)&fl[px * CP + g * 8] =
        *(const short8*)&fnh[((size_t)b * HW + px0 + px) * CCH + g * 8];
  }
  __syncthreads();

  const int w = tid >> 6, lane = tid & 63, lm = lane & 15, lk = lane >> 4;
  const int c0 = w * 16 + lk * 4;

  const short* sa = (const short*)spe_r + ((size_t)b * CCH + w * 16 + lm) * CCH;
  const short8 a1_0 = *(const short8*)&sa[lk * 8];
  const short8 a1_1 = *(const short8*)&sa[32 + lk * 8];

  f32x4 res[8];
  f32x4 xar[8];
#pragma unroll
  for (int nt = 0; nt < 8; ++nt) {
    const int prow = (nt * 16 + lm) * CP;
    short8 b0 = *(const short8*)&fl[prow + lk * 8];
    short8 b1 = *(const short8*)&fl[prow + 32 + lk * 8];
    f32x4 r = (f32x4){0.f, 0.f, 0.f, 0.f};
    r = __builtin_amdgcn_mfma_f32_16x16x32_bf16(a1_0, b0, r, 0, 0, 0);
    r = __builtin_amdgcn_mfma_f32_16x16x32_bf16(a1_1, b1, r, 0, 0, 0);
    res[nt] = r;
    ushort4_t pk;
    f32x4 xa;
#pragma unroll
    for (int j = 0; j < 4; ++j) {
      const float xv = xo[((size_t)b * CCH + c0 + j) * HW + px0 + nt * 16 + lm];
      xa[j] = 0.5f * (xv + r[j]);
      pk[j] = f2bf(xa[j]);
    }
    xar[nt] = xa;
    *(ushort4_t*)&xal[(nt * 16 + lm) * CP + c0] = pk;
  }
  __syncthreads();

  const short* wa = (const short*)wl_r + (w * 16 + lm) * CCH;
  const short8 a2_0 = *(const short8*)&wa[lk * 8];
  const short8 a2_1 = *(const short8*)&wa[32 + lk * 8];
  float blv[4];
#pragma unroll
  for (int j = 0; j < 4; ++j) blv[j] = bl[c0 + j];

#pragma unroll
  for (int nt = 0; nt < 8; ++nt) {
    const int prow = (nt * 16 + lm) * CP;
    short8 b0 = *(const short8*)&xal[prow + lk * 8];
    short8 b1 = *(const short8*)&xal[prow + 32 + lk * 8];
    f32x4 t = (f32x4){0.f, 0.f, 0.f, 0.f};
    t = __builtin_amdgcn_mfma_f32_16x16x32_bf16(a2_0, b0, t, 0, 0, 0);
    t = __builtin_amdgcn_mfma_f32_16x16x32_bf16(a2_1, b1, t, 0, 0, 0);
    ushort4_t fpk = *(const ushort4_t*)&fl[prow + c0];
#pragma unroll
    for (int j = 0; j < 4; ++j) {
      const float xl = lrelu(t[j] + blv[j]);
      const float wei = 1.f / (1.f + __expf(-xl));
      const float o = 2.f * xar[nt][j] * wei + res[nt][j] * (1.f - 2.f * wei) +
                      bf2f(fpk[j]);
      xo[((size_t)b * CCH + c0 + j) * HW + px0 + nt * 16 + lm] = o;
    }
  }
}

// ---------------------------------------------------------------------------
extern "C" void kernel_launch(void* const* d_in, const int* in_sizes, int n_in,
                              void* d_out, int out_size, void* d_ws,
                              size_t ws_size, hipStream_t stream) {
  const float* fea = (const float*)d_in[0];
  const float* spa = (const float*)d_in[1];
  const float* spe = (const float*)d_in[2];
  const float* W1  = (const float*)d_in[3];
  const float* W2  = (const float*)d_in[4];
  const float* Wl  = (const float*)d_in[5];
  const float* bl  = (const float*)d_in[6];
  float* out = (float*)d_out;

  // ws layout (bytes)
  const size_t FT_BYTES  = (size_t)BT * HW * CCH * 2;        // 32 MB
  const size_t FNH_BYTES = (size_t)BT * HW * CCH * 2;        // 32 MB
  const size_t SS_BYTES  = (size_t)4 * BT * PN * PK * 2;     // 7.5 MB
  char* wsb = (char*)d_ws;
  __hip_bfloat16* ft  = (__hip_bfloat16*)wsb;
  __hip_bfloat16* fnh = (__hip_bfloat16*)(wsb + FT_BYTES);
  __hip_bfloat16* ss  = (__hip_bfloat16*)(wsb + FT_BYTES + FNH_BYTES);
  char* wtb = wsb + FT_BYTES + FNH_BYTES + SS_BYTES;
  __hip_bfloat16* W1r   = (__hip_bfloat16*)wtb;                   // 18432 el
  __hip_bfloat16* W2r   = (__hip_bfloat16*)(wtb + 36864);         // 2048 el
  __hip_bfloat16* spe_r = (__hip_bfloat16*)(wtb + 36864 + 4096);  // 65536 el
  __hip_bfloat16* wl_r  = (__hip_bfloat16*)(wtb + 36864 + 4096 + 131072);

  prep_w_k<<<dim3(352), 256, 0, stream>>>(W1, W2, spe, Wl, W1r, W2r, spe_r, wl_r);
  fea_t_k<<<dim3(HW / 256, BT), 256, 0, stream>>>(fea, ft);
  spa_shift_k<<<dim3(4 * BT * PN * PK / 256), 256, 0, stream>>>(spa, ss);
  bblock_mfma_k<<<dim3(8, 8, BT), 512, 0, stream>>>(ft, W1r, W2r, fnh);
  spa_mfma_k<<<dim3(BT * 64), 512, 0, stream>>>(fnh, ss, out);
  final_mfma_k<<<dim3(HW / 128, BT), 256, 0, stream>>>(fnh, spe_r, wl_r, bl, out);
}

// Round 8
// 166.730 us; speedup vs baseline: 16.5053x; 1.6224x over previous
//
#include <hip/hip_runtime.h>
#include <hip/hip_bf16.h>
#include <hip/hip_runtime_api.h>

#define BT 16
#define CCH 64
#define H 128
#define W 128
#define STR 8
#define NH 15
#define NW 15
#define L 225
#define HW (H * W)

// us LDS pitch (bf16 elems per c-row); 16B-multiple
#define UPITCH 264
// conv LDS pitches
#define CP 72
#define MP 40

typedef __attribute__((ext_vector_type(8))) short short8;
typedef __attribute__((ext_vector_type(4))) float f32x4;
typedef __attribute__((ext_vector_type(4))) unsigned short ushort4_t;

__device__ __forceinline__ float lrelu(float v) { return v > 0.f ? v : 0.2f * v; }
__device__ __forceinline__ unsigned short f2bf(float v) {
  __hip_bfloat16 h = __float2bfloat16(v);
  unsigned short u;
  __builtin_memcpy(&u, &h, 2);
  return u;
}
__device__ __forceinline__ float bf2f(unsigned short u) {
  unsigned int x = ((unsigned int)u) << 16;
  float f;
  __builtin_memcpy(&f, &x, 4);
  return f;
}

// ---------------------------------------------------------------------------
// Prep: weights -> fragment order bf16 (W1r, W2r); spe/Wl -> bf16 row-major.
// ---------------------------------------------------------------------------
__global__ __launch_bounds__(256) void prep_w_k(
    const float* __restrict__ W1, const float* __restrict__ W2,
    const float* __restrict__ spe, const float* __restrict__ Wl,
    __hip_bfloat16* __restrict__ W1r, __hip_bfloat16* __restrict__ W2r,
    __hip_bfloat16* __restrict__ spe_r, __hip_bfloat16* __restrict__ wl_r) {
  const int idx = blockIdx.x * 256 + threadIdx.x;
  if (idx < 18432) {
    const int kk = idx >> 10, mc = (idx >> 5) & 31, ck = idx & 31;
    const int pos = kk >> 1, s = kk & 1;
    W1r[idx] = __float2bfloat16(W1[(mc * 64 + s * 32 + ck) * 9 + pos]);
    return;
  }
  int i = idx - 18432;
  if (i < 2048) { W2r[i] = __float2bfloat16(W2[i]); return; }
  i -= 2048;
  if (i < BT * CCH * CCH) { spe_r[i] = __float2bfloat16(spe[i]); return; }
  i -= BT * CCH * CCH;
  if (i < CCH * CCH) { wl_r[i] = __float2bfloat16(Wl[i]); return; }
}

// ---------------------------------------------------------------------------
// Prep: fea NCHW fp32 -> ft NHWC bf16.
// ---------------------------------------------------------------------------
__global__ __launch_bounds__(256) void fea_t_k(
    const float* __restrict__ fea, __hip_bfloat16* __restrict__ ft) {
  const int b = blockIdx.y;
  const int p0 = blockIdx.x * 256;
  const int tid = threadIdx.x;
#pragma unroll 1
  for (int it = 0; it < 8; ++it) {
    const int u = it * 256 + tid;
    const int px = u >> 3, g = u & 7;
    const int p = p0 + px;
    short8 v;
#pragma unroll
    for (int j = 0; j < 8; ++j)
      v[j] = (short)f2bf(fea[((size_t)b * CCH + g * 8 + j) * HW + p]);
    *(short8*)&ft[((size_t)b * HW + p) * CCH + g * 8] = v;
  }
}

// ---------------------------------------------------------------------------
// Prep: combined fold matrix T[b][pi][k] (bf16, dense 256x256):
//   pi=(yi,xi) output-grid, k=(ky,kx) input-grid (both 16x16, stride-8).
//   T[pi][k] = sum over v=(vy,vx) in {0,1}^2 of
//              spa[b][(yi-vy)*15+(xi-vx)][(ky-vy)*15+(kx-vx)]  (valid v only).
// Independent of (ky0,kx0): shared by all 64 blocks of a batch.
// ---------------------------------------------------------------------------
__global__ __launch_bounds__(256) void spa_comb_k(
    const float* __restrict__ spa, __hip_bfloat16* __restrict__ T) {
  const int bp = blockIdx.x;  // b*256 + pi
  const int b = bp >> 8, pi = bp & 255;
  const int k = threadIdx.x;
  const int yi = pi >> 4, xi = pi & 15;
  const int ky = k >> 4, kx = k & 15;
  const float* sb = spa + (size_t)b * L * L;
  float acc = 0.f;
#pragma unroll
  for (int vy = 0; vy < 2; ++vy)
#pragma unroll
    for (int vx = 0; vx < 2; ++vx) {
      const int py = yi - vy, px = xi - vx;
      const int qy = ky - vy, qx = kx - vx;
      if (py >= 0 && py < NH && px >= 0 && px < NW && qy >= 0 && qy < NH &&
          qx >= 0 && qx < NW)
        acc += sb[(py * NW + px) * L + qy * NW + qx];
    }
  T[(size_t)bp * 256 + k] = __float2bfloat16(acc);
}

// ---------------------------------------------------------------------------
// Kernel A (MFMA): BasicBlock implicit GEMM -> fnh NHWC bf16.
// ---------------------------------------------------------------------------
__global__ __launch_bounds__(512) void bblock_mfma_k(
    const __hip_bfloat16* __restrict__ ft, const __hip_bfloat16* __restrict__ W1r,
    const __hip_bfloat16* __restrict__ W2r, __hip_bfloat16* __restrict__ fnh) {
  __shared__ __align__(16) short st[324 * CP];
  __shared__ __align__(16) short mids[256 * MP];
  const int b = blockIdx.z, ty0 = blockIdx.y * 16, tx0 = blockIdx.x * 16;
  const int tid = threadIdx.x;

  for (int i = tid; i < 2592; i += 512) {
    const int px = i >> 3, g = i & 7;
    const int iy = px / 18, ix = px - iy * 18;
    int gy = ty0 + iy - 1;
    gy = gy < 0 ? -gy : (gy > 127 ? 254 - gy : gy);
    int gx = tx0 + ix - 1;
    gx = gx < 0 ? -gx : (gx > 127 ? 254 - gx : gx);
    *(short8*)&st[px * CP + g * 8] =
        *(const short8*)&ft[((size_t)b * HW + gy * W + gx) * CCH + g * 8];
  }
  __syncthreads();

  const int w = tid >> 6, lane = tid & 63, lm = lane & 15, lk = lane >> 4;
  const short* w1 = (const short*)W1r;
  const short* w2 = (const short*)W2r;

  f32x4 acc[2][2];
#pragma unroll
  for (int mt = 0; mt < 2; ++mt)
#pragma unroll
    for (int t = 0; t < 2; ++t) acc[mt][t] = (f32x4){0.f, 0.f, 0.f, 0.f};

#pragma unroll
  for (int pos = 0; pos < 9; ++pos) {
    const int dy = pos / 3, dx = pos - dy * 3;
#pragma unroll
    for (int s = 0; s < 2; ++s) {
      short8 a0 = *(const short8*)&w1[((pos * 2 + s) * 32 + lm) * 32 + lk * 8];
      short8 a1 = *(const short8*)&w1[((pos * 2 + s) * 32 + 16 + lm) * 32 + lk * 8];
#pragma unroll
      for (int t = 0; t < 2; ++t) {
        const int p = (w * 2 + t + dy) * 18 + lm + dx;
        short8 bb = *(const short8*)&st[p * CP + s * 32 + lk * 8];
        acc[0][t] = __builtin_amdgcn_mfma_f32_16x16x32_bf16(a0, bb, acc[0][t], 0, 0, 0);
        acc[1][t] = __builtin_amdgcn_mfma_f32_16x16x32_bf16(a1, bb, acc[1][t], 0, 0, 0);
      }
    }
  }

#pragma unroll
  for (int t = 0; t < 2; ++t) {
    const int n = (w * 2 + t) * 16 + lm;
#pragma unroll
    for (int mt = 0; mt < 2; ++mt) {
      ushort4_t pk;
#pragma unroll
      for (int r = 0; r < 4; ++r) pk[r] = f2bf(lrelu(acc[mt][t][r]));
      *(ushort4_t*)&mids[n * MP + mt * 16 + lk * 4] = pk;
    }
  }
  __syncthreads();

  f32x4 acc2[4][2];
#pragma unroll
  for (int m2 = 0; m2 < 4; ++m2)
#pragma unroll
    for (int t = 0; t < 2; ++t) acc2[m2][t] = (f32x4){0.f, 0.f, 0.f, 0.f};

  short8 b2[2];
#pragma unroll
  for (int t = 0; t < 2; ++t)
    b2[t] = *(const short8*)&mids[((w * 2 + t) * 16 + lm) * MP + lk * 8];
#pragma unroll
  for (int m2 = 0; m2 < 4; ++m2) {
    short8 a2 = *(const short8*)&w2[(m2 * 16 + lm) * 32 + lk * 8];
#pragma unroll
    for (int t = 0; t < 2; ++t)
      acc2[m2][t] = __builtin_amdgcn_mfma_f32_16x16x32_bf16(a2, b2[t], acc2[m2][t], 0, 0, 0);
  }

  unsigned short* fo = (unsigned short*)fnh;
#pragma unroll
  for (int m2 = 0; m2 < 4; ++m2)
#pragma unroll
    for (int t = 0; t < 2; ++t) {
      const int y = ty0 + w * 2 + t, x = tx0 + lm;
      ushort4_t pk;
#pragma unroll
      for (int r = 0; r < 4; ++r) pk[r] = f2bf(lrelu(acc2[m2][t][r]));
      *(ushort4_t*)&fo[((size_t)b * HW + y * W + x) * CCH + m2 * 16 + lk * 4] = pk;
    }
}

// ---------------------------------------------------------------------------
// Kernel B (MFMA): spatial-graph matmul + fold as ONE dense GEMM.
// Block = (b,ky0,kx0): x_grid[c][pi] = us[c][k] @ T[b][pi][k]^T,
// M=64, N=256, K=256. 8 waves = 2 mgroups x 4 ngroups.
// us staged once with bijective XOR swizzle on the 16B-block index:
//   blk' = (blk & ~7) | ((blk ^ (c>>3)) & 7)   (write AND read use blk').
// B streams from T (128KB/batch, L2-resident; XCD swizzle groups same-b
// blocks). One barrier; D stores straight to x.
// ---------------------------------------------------------------------------
__global__ __launch_bounds__(512) void spa_mfma_k(
    const __hip_bfloat16* __restrict__ fnh, const __hip_bfloat16* __restrict__ T,
    float* __restrict__ x) {
  __shared__ __align__(16) short us[CCH * UPITCH];  // 33.8 KB

  const int lb = ((int)blockIdx.x % 8) * 128 + (int)blockIdx.x / 8;
  const int b = lb >> 6, ky0 = (lb >> 3) & 7, kx0 = lb & 7;
  const int tid = threadIdx.x;

  const unsigned short* fb = (const unsigned short*)fnh + (size_t)b * HW * CCH;

  // stage us[c][k]: k = gy*16+gx (grid pixel), swizzled 16B-block columns
  for (int i = tid; i < 2048; i += 512) {
    const int pos = i >> 3, g = i & 7;
    const int gy = pos >> 4, gx = pos & 15;
    const int blk = pos >> 3;
    short8 v = *(const short8*)&fb[((ky0 + 8 * gy) * W + kx0 + 8 * gx) * CCH + g * 8];
#pragma unroll
    for (int e = 0; e < 8; ++e) {
      const int c = g * 8 + e;
      const int sblk = (blk & ~7) | ((blk ^ (c >> 3)) & 7);
      us[c * UPITCH + sblk * 8 + (pos & 7)] = v[e];
    }
  }
  __syncthreads();

  const int w = tid >> 6, lane = tid & 63;
  const int lm = lane & 15, lk = lane >> 4;
  const int mtg = w >> 2, ntg = w & 3;

  const short* tb = (const short*)T + (size_t)b * 256 * 256;

  f32x4 acc[2][4];
#pragma unroll
  for (int mt = 0; mt < 2; ++mt)
#pragma unroll
    for (int n = 0; n < 4; ++n) acc[mt][n] = (f32x4){0.f, 0.f, 0.f, 0.f};

  const int c0 = (mtg * 2) * 16 + lm, c1 = (mtg * 2 + 1) * 16 + lm;

#pragma unroll
  for (int k8 = 0; k8 < 8; ++k8) {
    const int kb = k8 * 4 + lk;  // 16B-block index of k0 = k8*32 + lk*8
    const int sb0 = (kb & ~7) | ((kb ^ (c0 >> 3)) & 7);
    const int sb1 = (kb & ~7) | ((kb ^ (c1 >> 3)) & 7);
    short8 a0 = *(const short8*)&us[c0 * UPITCH + sb0 * 8];
    short8 a1 = *(const short8*)&us[c1 * UPITCH + sb1 * 8];
    short8 bb[4];
#pragma unroll
    for (int n = 0; n < 4; ++n)
      bb[n] = *(const short8*)&tb[((ntg * 4 + n) * 16 + lm) * 256 + k8 * 32 + lk * 8];
#pragma unroll
    for (int n = 0; n < 4; ++n) {
      acc[0][n] = __builtin_amdgcn_mfma_f32_16x16x32_bf16(a0, bb[n], acc[0][n], 0, 0, 0);
      acc[1][n] = __builtin_amdgcn_mfma_f32_16x16x32_bf16(a1, bb[n], acc[1][n], 0, 0, 0);
    }
  }

  // store: c = (mtg*2+mt)*16 + lk*4 + r; pi = (ntg*4+n)*16+lm -> yi=ntg*4+n, xi=lm
  float* xb = x + (size_t)b * CCH * HW;
#pragma unroll
  for (int mt = 0; mt < 2; ++mt)
#pragma unroll
    for (int n = 0; n < 4; ++n) {
      const int row = (ntg * 4 + n) * 8 + ky0;
      const int col = lm * 8 + kx0;
#pragma unroll
      for (int r = 0; r < 4; ++r) {
        const int c = (mtg * 2 + mt) * 16 + lk * 4 + r;
        xb[(c * H + row) * W + col] = acc[mt][n][r];
      }
    }
}

// ---------------------------------------------------------------------------
// Kernel C (MFMA): spectral residual + gated fusion (unchanged).
// ---------------------------------------------------------------------------
__global__ __launch_bounds__(256) void final_mfma_k(
    const __hip_bfloat16* __restrict__ fnh, const __hip_bfloat16* __restrict__ spe_r,
    const __hip_bfloat16* __restrict__ wl_r, const float* __restrict__ bl,
    float* __restrict__ xo) {
  __shared__ __align__(16) short fl[128 * CP];
  __shared__ __align__(16) short xal[128 * CP];
  const int b = blockIdx.y;
  const int px0 = blockIdx.x * 128;
  const int tid = threadIdx.x;

  for (int i = tid; i < 128 * 8; i += 256) {
    const int px = i >> 3, g = i & 7;
    *(short8*)&fl[px * CP + g * 8] =
        *(const short8*)&fnh[((size_t)b * HW + px0 + px) * CCH + g * 8];
  }
  __syncthreads();

  const int w = tid >> 6, lane = tid & 63, lm = lane & 15, lk = lane >> 4;
  const int c0 = w * 16 + lk * 4;

  const short* sa = (const short*)spe_r + ((size_t)b * CCH + w * 16 + lm) * CCH;
  const short8 a1_0 = *(const short8*)&sa[lk * 8];
  const short8 a1_1 = *(const short8*)&sa[32 + lk * 8];

  f32x4 res[8];
  f32x4 xar[8];
#pragma unroll
  for (int nt = 0; nt < 8; ++nt) {
    const int prow = (nt * 16 + lm) * CP;
    short8 b0 = *(const short8*)&fl[prow + lk * 8];
    short8 b1 = *(const short8*)&fl[prow + 32 + lk * 8];
    f32x4 r = (f32x4){0.f, 0.f, 0.f, 0.f};
    r = __builtin_amdgcn_mfma_f32_16x16x32_bf16(a1_0, b0, r, 0, 0, 0);
    r = __builtin_amdgcn_mfma_f32_16x16x32_bf16(a1_1, b1, r, 0, 0, 0);
    res[nt] = r;
    ushort4_t pk;
    f32x4 xa;
#pragma unroll
    for (int j = 0; j < 4; ++j) {
      const float xv = xo[((size_t)b * CCH + c0 + j) * HW + px0 + nt * 16 + lm];
      xa[j] = 0.5f * (xv + r[j]);
      pk[j] = f2bf(xa[j]);
    }
    xar[nt] = xa;
    *(ushort4_t*)&xal[(nt * 16 + lm) * CP + c0] = pk;
  }
  __syncthreads();

  const short* wa = (const short*)wl_r + (w * 16 + lm) * CCH;
  const short8 a2_0 = *(const short8*)&wa[lk * 8];
  const short8 a2_1 = *(const short8*)&wa[32 + lk * 8];
  float blv[4];
#pragma unroll
  for (int j = 0; j < 4; ++j) blv[j] = bl[c0 + j];

#pragma unroll
  for (int nt = 0; nt < 8; ++nt) {
    const int prow = (nt * 16 + lm) * CP;
    short8 b0 = *(const short8*)&xal[prow + lk * 8];
    short8 b1 = *(const short8*)&xal[prow + 32 + lk * 8];
    f32x4 t = (f32x4){0.f, 0.f, 0.f, 0.f};
    t = __builtin_amdgcn_mfma_f32_16x16x32_bf16(a2_0, b0, t, 0, 0, 0);
    t = __builtin_amdgcn_mfma_f32_16x16x32_bf16(a2_1, b1, t, 0, 0, 0);
    ushort4_t fpk = *(const ushort4_t*)&fl[prow + c0];
#pragma unroll
    for (int j = 0; j < 4; ++j) {
      const float xl = lrelu(t[j] + blv[j]);
      const float wei = 1.f / (1.f + __expf(-xl));
      const float o = 2.f * xar[nt][j] * wei + res[nt][j] * (1.f - 2.f * wei) +
                      bf2f(fpk[j]);
      xo[((size_t)b * CCH + c0 + j) * HW + px0 + nt * 16 + lm] = o;
    }
  }
}

// ---------------------------------------------------------------------------
extern "C" void kernel_launch(void* const* d_in, const int* in_sizes, int n_in,
                              void* d_out, int out_size, void* d_ws,
                              size_t ws_size, hipStream_t stream) {
  const float* fea = (const float*)d_in[0];
  const float* spa = (const float*)d_in[1];
  const float* spe = (const float*)d_in[2];
  const float* W1  = (const float*)d_in[3];
  const float* W2  = (const float*)d_in[4];
  const float* Wl  = (const float*)d_in[5];
  const float* bl  = (const float*)d_in[6];
  float* out = (float*)d_out;

  // ws layout (bytes)
  const size_t FT_BYTES  = (size_t)BT * HW * CCH * 2;   // 32 MB
  const size_t FNH_BYTES = (size_t)BT * HW * CCH * 2;   // 32 MB
  const size_t T_BYTES   = (size_t)BT * 256 * 256 * 2;  // 2 MB
  char* wsb = (char*)d_ws;
  __hip_bfloat16* ft  = (__hip_bfloat16*)wsb;
  __hip_bfloat16* fnh = (__hip_bfloat16*)(wsb + FT_BYTES);
  __hip_bfloat16* T   = (__hip_bfloat16*)(wsb + FT_BYTES + FNH_BYTES);
  char* wtb = wsb + FT_BYTES + FNH_BYTES + T_BYTES;
  __hip_bfloat16* W1r   = (__hip_bfloat16*)wtb;                   // 18432 el
  __hip_bfloat16* W2r   = (__hip_bfloat16*)(wtb + 36864);         // 2048 el
  __hip_bfloat16* spe_r = (__hip_bfloat16*)(wtb + 36864 + 4096);  // 65536 el
  __hip_bfloat16* wl_r  = (__hip_bfloat16*)(wtb + 36864 + 4096 + 131072);

  prep_w_k<<<dim3(352), 256, 0, stream>>>(W1, W2, spe, Wl, W1r, W2r, spe_r, wl_r);
  fea_t_k<<<dim3(HW / 256, BT), 256, 0, stream>>>(fea, ft);
  spa_comb_k<<<dim3(BT * 256), 256, 0, stream>>>(spa, T);
  bblock_mfma_k<<<dim3(8, 8, BT), 512, 0, stream>>>(ft, W1r, W2r, fnh);
  spa_mfma_k<<<dim3(BT * 64), 512, 0, stream>>>(fnh, T, out);
  final_mfma_k<<<dim3(HW / 128, BT), 256, 0, stream>>>(fnh, spe_r, wl_r, bl, out);
}